// Round 9
// baseline (431.595 us; speedup 1.0000x reference)
//
#include <hip/hip_runtime.h>
#include <hip/hip_bf16.h>
#include <hip/hip_fp16.h>
#include <cstddef>

#define NNODES 50000
#define NEDGES 800000
#define HID 128
#define NHEAD 8
#define AGG_NB (NNODES / 16)                           // 3125 (4 nodes per wave, 4 waves/block)
#define NSLICE 64                                      // stats slices (R7/R8-proven contention level)
#define SLAYER (NSLICE * 512)                          // floats per layer of slice storage

// ---- binned CSR build
#define NBUCK 196                                      // ceil(50000/256) node-range buckets
#define BCH 2048                                       // edges per bin_scatter block
#define BIN_NB ((NEDGES + BCH - 1) / BCH)              // 391

typedef __attribute__((ext_vector_type(4))) float floatx4;
typedef _Float16 __attribute__((ext_vector_type(8))) half8;
typedef _Float16 __attribute__((ext_vector_type(2))) half2v;

static inline size_t align_up(size_t x, size_t a) { return (x + a - 1) & ~(a - 1); }

__device__ inline float fexp2(float x) {
#if __has_builtin(__builtin_amdgcn_exp2f)
    return __builtin_amdgcn_exp2f(x);          // raw v_exp_f32
#else
    return __expf(x * 0.69314718055994531f);   // e^(x ln2) = 2^x
#endif
}

__device__ inline unsigned short f2h(float f) {
    return __builtin_bit_cast(unsigned short, (_Float16)f);   // v_cvt_f16_f32 (RTE)
}

// ---------------------------------------------------------------- init: wconv (f32->f16) + all zero-fill (1 dispatch)
__global__ __launch_bounds__(256) void init_kernel(const float* __restrict__ W1,
                                                   const float* __restrict__ W2,
                                                   const float* __restrict__ W3,
                                                   unsigned short* __restrict__ Wt,
                                                   int* __restrict__ zeroA, int nA,
                                                   float* __restrict__ zeroB, int nB) {
    int b = blockIdx.x;
    int t = threadIdx.x;
    if (b < 192) {
        int layer = b >> 6;
        const float* W = (layer == 0) ? W1 : ((layer == 1) ? W2 : W3);
        int idx = (b & 63) * 256 + t;   // k*128+n
        int n = idx & 127;
        int k = idx >> 7;
        Wt[layer * 16384 + n * 128 + k] = f2h(W[idx]);
    } else {
        int nb = gridDim.x - 192;
        int bb = b - 192;
        for (int i = bb * 256 + t; i < nA; i += nb * 256) zeroA[i] = 0;
        for (int i = bb * 256 + t; i < nB; i += nb * 256) zeroB[i] = 0.f;
    }
}

// ---------------------------------------------------------------- binned CSR build (no per-edge global atomics)
// bucket = dst >> 8 (256 nodes per bucket). Entry pack: src(16b) | local_dst(8b)<<16.
__global__ __launch_bounds__(256) void bin_count_kernel(const int* __restrict__ edge,
                                                        int* __restrict__ bucketCnt) {
    __shared__ int h[NBUCK];
    int t = threadIdx.x;
    if (t < NBUCK) h[t] = 0;
    __syncthreads();
    for (int i = blockIdx.x * 256 + t; i < NEDGES; i += gridDim.x * 256)
        atomicAdd(&h[edge[NEDGES + i] >> 8], 1);
    __syncthreads();
    if (t < NBUCK && h[t]) atomicAdd(&bucketCnt[t], h[t]);
}

// one block: exclusive scan of 196 bucket counts (removes inline scans from 587 blocks)
__global__ __launch_bounds__(256) void bucket_scan_kernel(const int* __restrict__ bucketCnt,
                                                          int* __restrict__ bucketBase) {
    __shared__ int sA[256];
    int t = threadIdx.x;
    int v = (t < NBUCK) ? bucketCnt[t] : 0;
    sA[t] = v;
    __syncthreads();
    for (int off = 1; off < 256; off <<= 1) {
        int x = (t >= off) ? sA[t - off] : 0;
        __syncthreads();
        sA[t] += x;
        __syncthreads();
    }
    if (t < NBUCK) bucketBase[t] = sA[t] - v;
    if (t == 0) bucketBase[NBUCK] = NEDGES;
}

// one 2048-edge chunk per block: LDS rank -> LDS bucket-sorted reorder -> coalesced copy-out.
__global__ __launch_bounds__(256) void bin_scatter_kernel(const int* __restrict__ edge,
                                                          const int* __restrict__ bucketBase,
                                                          int* __restrict__ bucketCursor,
                                                          unsigned int* __restrict__ binned) {
    __shared__ int sA[256];
    __shared__ int hcnt[NBUCK];
    __shared__ int hbase[NBUCK];
    __shared__ int gbase[NBUCK];
    __shared__ unsigned int sEnt[BCH];
    __shared__ unsigned char sBk[BCH];
    int t = threadIdx.x;
    int e0 = blockIdx.x * BCH;
    int nv = NEDGES - e0;
    if (nv > BCH) nv = BCH;

    if (t < NBUCK) hcnt[t] = 0;
    __syncthreads();

    int myB[8];
    int myR[8];
    unsigned int myP[8];
    #pragma unroll
    for (int j = 0; j < 8; ++j) {
        int idx = j * 256 + t;
        myB[j] = -1;
        if (idx < nv) {
            int s = edge[e0 + idx];
            int d = edge[NEDGES + e0 + idx];
            int bk = d >> 8;
            myB[j] = bk;
            myP[j] = (unsigned)s | ((unsigned)(d & 255) << 16);
            myR[j] = atomicAdd(&hcnt[bk], 1);    // LDS atomic, rank within (chunk,bucket)
        }
    }
    __syncthreads();
    int hc = (t < NBUCK) ? hcnt[t] : 0;
    sA[t] = hc;
    __syncthreads();
    for (int off = 1; off < 256; off <<= 1) {
        int x = (t >= off) ? sA[t - off] : 0;
        __syncthreads();
        sA[t] += x;
        __syncthreads();
    }
    if (t < NBUCK) {
        hbase[t] = sA[t] - hc;                               // chunk-local exclusive base
        gbase[t] = bucketBase[t] + atomicAdd(&bucketCursor[t], hc);  // one global atomic per (chunk,bucket)
    }
    __syncthreads();
    #pragma unroll
    for (int j = 0; j < 8; ++j) {
        if (myB[j] >= 0) {
            int p = hbase[myB[j]] + myR[j];
            sEnt[p] = myP[j];
            sBk[p] = (unsigned char)myB[j];
        }
    }
    __syncthreads();
    #pragma unroll
    for (int j = 0; j < 8; ++j) {
        int i = j * 256 + t;
        if (i < nv) {
            int bk = sBk[i];
            binned[gbase[bk] + (i - hbase[bk])] = sEnt[i];   // sorted order -> coalesced runs
        }
    }
}

// one block per bucket: per-node hist+cursor entirely in LDS; csr writes stay in a ~16KB region.
__global__ __launch_bounds__(256) void fine_csr_kernel(const int* __restrict__ bucketCnt,
                                                       const int* __restrict__ bucketBase,
                                                       const unsigned int* __restrict__ binned,
                                                       int* __restrict__ offs,
                                                       int* __restrict__ csr) {
    __shared__ int sA[256];
    __shared__ int sB[256];
    int t = threadIdx.x;
    int b = blockIdx.x;
    int cntb = bucketCnt[b];
    int base = bucketBase[b];           // bucket's edge-region base
    sB[t] = 0;
    __syncthreads();
    for (int i = t; i < cntb; i += 256)
        atomicAdd(&sB[(binned[base + i] >> 16) & 255], 1);
    __syncthreads();
    int nc = sB[t];
    sA[t] = nc;
    __syncthreads();
    for (int off = 1; off < 256; off <<= 1) {
        int x = (t >= off) ? sA[t - off] : 0;
        __syncthreads();
        sA[t] += x;
        __syncthreads();
    }
    int nodeBase = base + sA[t] - nc;   // global csr start for this node
    int gid = b * 256 + t;
    if (gid < NNODES) offs[gid] = nodeBase;
    if (b == NBUCK - 1 && t == 0) offs[NNODES] = NEDGES;
    sB[t] = nodeBase;                   // becomes the LDS cursor (global positions)
    __syncthreads();
    for (int i = t; i < cntb; i += 256) {
        unsigned e = binned[base + i];
        int pos = atomicAdd(&sB[(e >> 16) & 255], 1);
        csr[pos] = (int)(e & 0xFFFFu);
    }
}

// ---------------------------------------------------------------- bn finalize: 64 slices -> scale/shift vector
__global__ __launch_bounds__(256) void bn_finalize_kernel(const float* __restrict__ statsPart,
                                                          const float* __restrict__ g,
                                                          const float* __restrict__ b,
                                                          float* __restrict__ ssv) {
    __shared__ float sm[256];
    int t = threadIdx.x;
    // t<128 sums s, t>=128 sums s2 (halves the serial chain)
    const float* base = statsPart + (t & 127) + ((t >> 7) << 7);
    float s = 0.f;
    #pragma unroll 8
    for (int k = 0; k < NSLICE; ++k) s += base[k * 512];
    sm[t] = s;
    __syncthreads();
    if (t < 128) {
        float mu = sm[t] / (float)NNODES;
        float var = sm[128 + t] / (float)NNODES - mu * mu;
        float rstd = rsqrtf(var + 1e-5f);
        float scale = g[t] * rstd;
        ssv[t] = scale;
        ssv[128 + t] = b[t] - mu * scale;
    }
}

// ---------------------------------------------------------------- MFMA GEMM [N,128]x[128,128]  (f16 pipeline)
//   mode 0: X = Xin
//   mode 1: X = elu(bn(Xin)); also write X to Hw (=h1, skip source)
//   mode 2: X = skip + elu(bn(Xin))   (h3_in never materialized)
// R17: MAX TLP. Wave = 16 rows x 32 output channels (2 h-blocks, 8 MFMAs).
// Grid 3125 blocks x 4 waves = 12500 waves (2x R6, 4x R8) — latency hiding by
// wave count, the variable that tracked every gemm delta R5-R8. The 4 waves
// of a block share the same 16 A-rows (L1-hit for 3 of 4). B direct from
// L1-hot Wt; bf1 issue slides under hb0's MFMAs. launch_bounds(256,6): VGPR
// cap 85 -> 24 waves/CU resident. Zero barriers; LDS = wave-local transpose.
// esrc/edst are pre-scaled by log2(e) so aggregate uses raw v_exp_f32.
#define GROWS 16
#define TSTRIDE 40
#define LOG2E 1.4426950408889634f
__global__ __launch_bounds__(256, 6) void gemm_kernel(const float* __restrict__ Xin,
                                                      const float* __restrict__ skip,
                                                      const float* __restrict__ ssv,
                                                      const unsigned short* __restrict__ Wt,
                                                      const float* __restrict__ a,
                                                      float* __restrict__ Hw,
                                                      unsigned short* __restrict__ Hb,
                                                      float* __restrict__ esrc,
                                                      float* __restrict__ edst,
                                                      int mode) {
    __shared__ unsigned short As[4 * 16 * TSTRIDE];   // per-wave transpose region
    int tid = threadIdx.x;
    int wv = tid >> 6;                       // wave owns heads {2wv, 2wv+1}
    int lane = tid & 63;
    int l15 = lane & 15;
    int quad = lane >> 4;
    int rowBase = blockIdx.x * GROWS;
    int gr = rowBase + l15;                  // 3125*16 == 50000: always valid
    bool valid = gr < NNODES;

    // ---- A loads (8x float4) + B hb0 loads issued up front
    float4 va[8];
    if (valid) {
        const float* xr = Xin + (size_t)gr * HID + quad * 8;
        #pragma unroll
        for (int c = 0; c < 4; ++c) {
            va[2 * c]     = *(const float4*)(xr + c * 32);
            va[2 * c + 1] = *(const float4*)(xr + c * 32 + 4);
        }
    } else {
        #pragma unroll
        for (int j = 0; j < 8; ++j) va[j] = make_float4(0.f, 0.f, 0.f, 0.f);
    }
    half8 bf0[4];
    {
        const unsigned short* wb = Wt + ((2 * wv) * 16 + l15) * 128 + quad * 8;
        #pragma unroll
        for (int c = 0; c < 4; ++c) bf0[c] = *(const half8*)(wb + c * 32);
    }

    // ---- fused prev-layer bn+elu(+skip) on the A fragment
    if (mode >= 1 && valid) {
        #pragma unroll
        for (int c = 0; c < 4; ++c) {
            #pragma unroll
            for (int hh = 0; hh < 2; ++hh) {
                int ch = quad * 8 + c * 32 + hh * 4;
                float4 sc = *(const float4*)(ssv + ch);
                float4 sh = *(const float4*)(ssv + 128 + ch);
                float4 v = va[2 * c + hh];
                v.x = sc.x * v.x + sh.x;
                v.y = sc.y * v.y + sh.y;
                v.z = sc.z * v.z + sh.z;
                v.w = sc.w * v.w + sh.w;
                v.x = (v.x > 0.f) ? v.x : expm1f(v.x);
                v.y = (v.y > 0.f) ? v.y : expm1f(v.y);
                v.z = (v.z > 0.f) ? v.z : expm1f(v.z);
                v.w = (v.w > 0.f) ? v.w : expm1f(v.w);
                if (mode == 2) {
                    const float* sr = skip + (size_t)gr * HID + ch;
                    float4 s = *(const float4*)sr;
                    v.x += s.x; v.y += s.y; v.z += s.z; v.w += s.w;
                }
                va[2 * c + hh] = v;
            }
        }
        if (mode == 1 && wv == 0) {
            float* hw = Hw + (size_t)gr * HID + quad * 8;
            #pragma unroll
            for (int c = 0; c < 4; ++c) {
                *(float4*)(hw + c * 32)     = va[2 * c];
                *(float4*)(hw + c * 32 + 4) = va[2 * c + 1];
            }
        }
    }
    half8 af[4];
    #pragma unroll
    for (int c = 0; c < 4; ++c) {
        uint4 pk;
        pk.x = __builtin_bit_cast(unsigned int, __builtin_amdgcn_cvt_pkrtz(va[2*c].x,   va[2*c].y));
        pk.y = __builtin_bit_cast(unsigned int, __builtin_amdgcn_cvt_pkrtz(va[2*c].z,   va[2*c].w));
        pk.z = __builtin_bit_cast(unsigned int, __builtin_amdgcn_cvt_pkrtz(va[2*c+1].x, va[2*c+1].y));
        pk.w = __builtin_bit_cast(unsigned int, __builtin_amdgcn_cvt_pkrtz(va[2*c+1].z, va[2*c+1].w));
        af[c] = __builtin_bit_cast(half8, pk);
    }

    // ---- bf1 issue (hides under hb0 MFMAs), then 8 MFMAs
    half8 bf1[4];
    {
        const unsigned short* wb = Wt + ((2 * wv + 1) * 16 + l15) * 128 + quad * 8;
        #pragma unroll
        for (int c = 0; c < 4; ++c) bf1[c] = *(const half8*)(wb + c * 32);
    }
    floatx4 acc0 = (floatx4){0.f, 0.f, 0.f, 0.f};
    floatx4 acc1 = (floatx4){0.f, 0.f, 0.f, 0.f};
    #pragma unroll
    for (int c = 0; c < 4; ++c)
        acc0 = __builtin_amdgcn_mfma_f32_16x16x32_f16(af[c], bf0[c], acc0, 0, 0, 0);
    #pragma unroll
    for (int c = 0; c < 4; ++c)
        acc1 = __builtin_amdgcn_mfma_f32_16x16x32_f16(af[c], bf1[c], acc1, 0, 0, 0);

    // ---- wave-local transpose through LDS (per-wave region, no barrier;
    // per-wave DS ops execute in order)
    unsigned short* ws = &As[wv * 16 * TSTRIDE];
    #pragma unroll
    for (int reg = 0; reg < 4; ++reg) {
        ws[(quad * 4 + reg) * TSTRIDE + l15]      = f2h(acc0[reg]);
        ws[(quad * 4 + reg) * TSTRIDE + 16 + l15] = f2h(acc1[reg]);
    }

    // ---- Hb store: all 64 lanes (16 rows x 4 segs of 8 f16)
    {
        int rloc = lane >> 2;
        int seg = lane & 3;
        int grow = rowBase + rloc;
        uint4 u = *(const uint4*)(&ws[rloc * TSTRIDE + seg * 8]);
        if (grow < NNODES)
            *(uint4*)(Hb + (size_t)grow * HID + wv * 32 + seg * 8) = u;
    }

    // ---- es/ev epilogue: lanes 0-31 = (row, head-of-pair)
    if (lane < 32) {
        int rloc = lane >> 1;
        int lb = lane & 1;
        int grow = rowBase + rloc;
        const unsigned short* rrow = &ws[rloc * TSTRIDE + lb * 16];
        uint4 u0 = *(const uint4*)(rrow);
        uint4 u1 = *(const uint4*)(rrow + 8);
        if (grow < NNODES) {
            float f[16];
            unsigned int* pu = (unsigned int*)&u0;
            #pragma unroll
            for (int j = 0; j < 4; ++j) {
                half2v hv = __builtin_bit_cast(half2v, pu[j]);
                f[2 * j]     = (float)hv[0];
                f[2 * j + 1] = (float)hv[1];
            }
            pu = (unsigned int*)&u1;
            #pragma unroll
            for (int j = 0; j < 4; ++j) {
                half2v hv = __builtin_bit_cast(half2v, pu[j]);
                f[8 + 2 * j]     = (float)hv[0];
                f[8 + 2 * j + 1] = (float)hv[1];
            }
            int head = wv * 2 + lb;
            float es = 0.f, ev = 0.f;
            #pragma unroll
            for (int j = 0; j < 16; ++j) {
                es += f[j] * a[head * 32 + j];
                ev += f[j] * a[head * 32 + 16 + j];
            }
            esrc[grow * NHEAD + head] = es * LOG2E;
            edst[grow * NHEAD + head] = ev * LOG2E;
        }
    }
}

// ---------------------------------------------------------------- softmax aggregation + sliced BN stats
// 4 nodes per wave (16 lanes/node, 8 channels/lane, uint4 Hb gathers).
// f16 h (v_fma_mix unpack), raw v_exp_f32 (log2e pre-folded), fmax LeakyReLU.
// Epilogue: 16-node LDS matrix -> 64-sliced global atomics.
__global__ __launch_bounds__(256) void aggregate_kernel(const int* __restrict__ offs,
                                                        const int* __restrict__ csr,
                                                        const float* __restrict__ esrc,
                                                        const float* __restrict__ edst,
                                                        const unsigned int* __restrict__ Hb,
                                                        float* __restrict__ out,
                                                        float* __restrict__ statsPart) {
    int tid = threadIdx.x;
    int wv = tid >> 6;
    int lane = tid & 63;
    int grp = lane >> 4;               // 4 node-groups per wave
    int sub = lane & 15;               // owns channels sub*8 .. sub*8+7
    int head = sub >> 1;
    int n = blockIdx.x * 16 + wv * 4 + grp;
    int beg = offs[n], end = offs[n + 1];
    float ed = edst[n * NHEAD + head];
    float acc[8];
    #pragma unroll
    for (int q = 0; q < 8; ++q) acc[q] = 0.f;
    float den = 0.f;
    for (int i = beg; i < end; i += 4) {
        int ss[4];
        #pragma unroll
        for (int j = 0; j < 4; ++j)
            ss[j] = csr[min(i + j, end - 1)];     // clamp: dup load, masked below
        float ee[4];
        uint4 hh[4];
        #pragma unroll
        for (int j = 0; j < 4; ++j)
            ee[j] = esrc[(unsigned)ss[j] * 8u + (unsigned)head];
        #pragma unroll
        for (int j = 0; j < 4; ++j)
            hh[j] = *(const uint4*)(Hb + (unsigned)ss[j] * 64u + (unsigned)sub * 4u);
        #pragma unroll
        for (int j = 0; j < 4; ++j) {
            float e = ee[j] + ed;
            e = fmaxf(e, 0.2f * e);               // LeakyReLU (pos-homog, log2e pre-folded)
            float w = fexp2(e);
            w = (i + j < end) ? w : 0.f;
            den += w;
            half2v h0 = __builtin_bit_cast(half2v, hh[j].x);
            half2v h1 = __builtin_bit_cast(half2v, hh[j].y);
            half2v h2 = __builtin_bit_cast(half2v, hh[j].z);
            half2v h3 = __builtin_bit_cast(half2v, hh[j].w);
            acc[0] += w * (float)h0[0];           // v_fma_mix_f32
            acc[1] += w * (float)h0[1];
            acc[2] += w * (float)h1[0];
            acc[3] += w * (float)h1[1];
            acc[4] += w * (float)h2[0];
            acc[5] += w * (float)h2[1];
            acc[6] += w * (float)h3[0];
            acc[7] += w * (float)h3[1];
        }
    }
    float inv = 1.f / (den + 1e-16f);
    float4 o0 = make_float4(acc[0] * inv, acc[1] * inv, acc[2] * inv, acc[3] * inv);
    float4 o1 = make_float4(acc[4] * inv, acc[5] * inv, acc[6] * inv, acc[7] * inv);
    float* orow = out + (size_t)n * HID + sub * 8;
    *(float4*)orow = o0;
    *(float4*)(orow + 4) = o1;

    // ---- BN partials: 16-node LDS matrix (pad stride 136), one barrier,
    // then 64-sliced global atomics.
    __shared__ float sm[16 * 136];
    float* srow = &sm[(wv * 4 + grp) * 136 + sub * 8];
    *(float4*)srow = o0;
    *(float4*)(srow + 4) = o1;
    __syncthreads();
    if (tid < 128) {
        float s = 0.f, s2 = 0.f;
        #pragma unroll
        for (int rr = 0; rr < 16; ++rr) {
            float v = sm[rr * 136 + tid];
            s += v;
            s2 += v * v;
        }
        float* slice = statsPart + (blockIdx.x & (NSLICE - 1)) * 512;
        atomicAdd(&slice[tid], s);
        atomicAdd(&slice[128 + tid], s2);
    }
}

// ---------------------------------------------------------------- final: apply BN from precomputed ssv
__global__ __launch_bounds__(256) void final_apply_kernel(const float* __restrict__ X,
                                                          const float* __restrict__ ssv,
                                                          float* __restrict__ out) {
    __shared__ float ssm[256];
    int tid = threadIdx.x;
    ssm[tid] = ssv[tid];
    __syncthreads();
    int total4 = NNODES * HID / 4;
    for (int i = blockIdx.x * 256 + tid; i < total4; i += gridDim.x * 256) {
        float4 v = ((const float4*)X)[i];
        int c4 = (i & 31) * 4;
        float4 sc = *(const float4*)(ssm + c4);
        float4 sh = *(const float4*)(ssm + 128 + c4);
        v.x = sc.x * v.x + sh.x;
        v.y = sc.y * v.y + sh.y;
        v.z = sc.z * v.z + sh.z;
        v.w = sc.w * v.w + sh.w;
        ((float4*)out)[i] = v;
    }
}

// ---------------------------------------------------------------- launch (15 dispatches)
extern "C" void kernel_launch(void* const* d_in, const int* in_sizes, int n_in,
                              void* d_out, int out_size, void* d_ws, size_t ws_size,
                              hipStream_t stream) {
    const float* x   = (const float*)d_in[0];
    const int* edge  = (const int*)d_in[1];
    const float* W1  = (const float*)d_in[2];
    const float* a1  = (const float*)d_in[3];
    const float* W2  = (const float*)d_in[4];
    const float* a2  = (const float*)d_in[5];
    const float* W3  = (const float*)d_in[6];
    const float* a3  = (const float*)d_in[7];
    const float* g1  = (const float*)d_in[8];
    const float* b1  = (const float*)d_in[9];
    const float* g2  = (const float*)d_in[10];
    const float* b2  = (const float*)d_in[11];
    const float* g3  = (const float*)d_in[12];
    const float* b3  = (const float*)d_in[13];
    float* outp      = (float*)d_out;

    char* p = (char*)d_ws;
    size_t cur = 0;
    auto carve = [&](size_t bytes) {
        void* r = p + cur;
        cur = align_up(cur + bytes, 256);
        return r;
    };
    int*   offs   = (int*)carve((NNODES + 1) * sizeof(int));
    int*   csr    = (int*)carve(NEDGES * sizeof(int));
    unsigned short* wt = (unsigned short*)carve(3 * 16384 * sizeof(unsigned short));
    unsigned short* hb = (unsigned short*)carve((size_t)NNODES * HID * sizeof(unsigned short));
    float* agg    = (float*)carve((size_t)NNODES * HID * sizeof(float));
    float* h1     = (float*)carve((size_t)NNODES * HID * sizeof(float));
    float* esrc   = (float*)carve((size_t)NNODES * NHEAD * sizeof(float));
    float* edst   = (float*)carve((size_t)NNODES * NHEAD * sizeof(float));
    float* stats  = (float*)carve(3 * SLAYER * sizeof(float));   // 64 slices x 512 floats x 3 layers
    int*   bcnt   = (int*)carve((3 * NBUCK + 1) * sizeof(int));  // bucketCnt + bucketCursor + bucketBase
    int*   bcur   = bcnt + NBUCK;
    int*   bbase  = bcnt + 2 * NBUCK;
    float* ssv    = (float*)carve(3 * 256 * sizeof(float));      // per-layer scale|shift
    float* stats1 = stats;
    float* stats2 = stats + SLAYER;
    float* stats3 = stats + 2 * SLAYER;
    float* ssv1 = ssv;
    float* ssv2 = ssv + 256;
    float* ssv3 = ssv + 512;
    // binned edge array (4B packed entries) aliases h1: h1 is first written by
    // gemm layer-2 (mode 1), strictly after fine_csr_kernel has consumed binned.
    unsigned int* binned = (unsigned int*)h1;

    const int GB = (NNODES + GROWS - 1) / GROWS;   // 3125

    // ---- init (wconv + zero bucket counters/cursors + zero stats) + binned CSR build
    init_kernel<<<256, 256, 0, stream>>>(W1, W2, W3, wt,
                                         bcnt, 2 * NBUCK,
                                         stats, 3 * SLAYER);
    bin_count_kernel<<<256, 256, 0, stream>>>(edge, bcnt);
    bucket_scan_kernel<<<1, 256, 0, stream>>>(bcnt, bbase);
    bin_scatter_kernel<<<BIN_NB, 256, 0, stream>>>(edge, bbase, bcur, binned);
    fine_csr_kernel<<<NBUCK, 256, 0, stream>>>(bcnt, bbase, binned, offs, csr);

    // ---- layer 1
    gemm_kernel<<<GB, 256, 0, stream>>>(x, nullptr, nullptr,
                                        wt, a1, nullptr, hb, esrc, edst, 0);
    aggregate_kernel<<<AGG_NB, 256, 0, stream>>>(offs, csr, esrc, edst,
                                                 (const unsigned int*)hb, agg, stats1);
    bn_finalize_kernel<<<1, 256, 0, stream>>>(stats1, g1, b1, ssv1);

    // ---- layer 2 (gemm applies elu(bn1(agg)) inline, writes h1)
    gemm_kernel<<<GB, 256, 0, stream>>>(agg, nullptr, ssv1,
                                        wt + 16384, a2, h1, hb, esrc, edst, 1);
    aggregate_kernel<<<AGG_NB, 256, 0, stream>>>(offs, csr, esrc, edst,
                                                 (const unsigned int*)hb, agg, stats2);
    bn_finalize_kernel<<<1, 256, 0, stream>>>(stats2, g2, b2, ssv2);

    // ---- layer 3 (gemm applies h1 + elu(bn2(agg)) inline)
    gemm_kernel<<<GB, 256, 0, stream>>>(agg, h1, ssv2,
                                        wt + 32768, a3, nullptr, hb, esrc, edst, 2);
    aggregate_kernel<<<AGG_NB, 256, 0, stream>>>(offs, csr, esrc, edst,
                                                 (const unsigned int*)hb, agg, stats3);
    bn_finalize_kernel<<<1, 256, 0, stream>>>(stats3, g3, b3, ssv3);

    // ---- final (applies bn3)
    final_apply_kernel<<<768, 256, 0, stream>>>(agg, ssv3, outp);
}

// Round 10
// 373.369 us; speedup vs baseline: 1.1559x; 1.1559x over previous
//
#include <hip/hip_runtime.h>
#include <hip/hip_bf16.h>
#include <hip/hip_fp16.h>
#include <cstddef>

#define NNODES 50000
#define NEDGES 800000
#define HID 128
#define NHEAD 8
#define AGG_NB (NNODES / 16)                           // 3125 (4 nodes per wave, 4 waves/block)
#define NSLICE 64                                      // stats slices
#define SLAYER (NSLICE * 512)                          // floats per layer of slice storage

// ---- binned CSR build
#define NBUCK 196                                      // ceil(50000/256) node-range buckets
#define BCH 2048                                       // edges per bin_scatter block
#define BIN_NB ((NEDGES + BCH - 1) / BCH)              // 391

typedef __attribute__((ext_vector_type(4))) float floatx4;
typedef _Float16 __attribute__((ext_vector_type(8))) half8;
typedef _Float16 __attribute__((ext_vector_type(2))) half2v;

static inline size_t align_up(size_t x, size_t a) { return (x + a - 1) & ~(a - 1); }

__device__ inline float fexp2(float x) {
#if __has_builtin(__builtin_amdgcn_exp2f)
    return __builtin_amdgcn_exp2f(x);          // raw v_exp_f32
#else
    return __expf(x * 0.69314718055994531f);   // e^(x ln2) = 2^x
#endif
}

__device__ inline unsigned short f2h(float f) {
    return __builtin_bit_cast(unsigned short, (_Float16)f);   // v_cvt_f16_f32 (RTE)
}

// ---------------------------------------------------------------- init: wconv (f32->f16) + all zero-fill (1 dispatch)
__global__ __launch_bounds__(256) void init_kernel(const float* __restrict__ W1,
                                                   const float* __restrict__ W2,
                                                   const float* __restrict__ W3,
                                                   unsigned short* __restrict__ Wt,
                                                   int* __restrict__ zeroA, int nA,
                                                   float* __restrict__ zeroB, int nB) {
    int b = blockIdx.x;
    int t = threadIdx.x;
    if (b < 192) {
        int layer = b >> 6;
        const float* W = (layer == 0) ? W1 : ((layer == 1) ? W2 : W3);
        int idx = (b & 63) * 256 + t;   // k*128+n
        int n = idx & 127;
        int k = idx >> 7;
        Wt[layer * 16384 + n * 128 + k] = f2h(W[idx]);
    } else {
        int nb = gridDim.x - 192;
        int bb = b - 192;
        for (int i = bb * 256 + t; i < nA; i += nb * 256) zeroA[i] = 0;
        for (int i = bb * 256 + t; i < nB; i += nb * 256) zeroB[i] = 0.f;
    }
}

// ---------------------------------------------------------------- binned CSR build (no per-edge global atomics)
__global__ __launch_bounds__(256) void bin_count_kernel(const int* __restrict__ edge,
                                                        int* __restrict__ bucketCnt) {
    __shared__ int h[NBUCK];
    int t = threadIdx.x;
    if (t < NBUCK) h[t] = 0;
    __syncthreads();
    for (int i = blockIdx.x * 256 + t; i < NEDGES; i += gridDim.x * 256)
        atomicAdd(&h[edge[NEDGES + i] >> 8], 1);
    __syncthreads();
    if (t < NBUCK && h[t]) atomicAdd(&bucketCnt[t], h[t]);
}

__global__ __launch_bounds__(256) void bucket_scan_kernel(const int* __restrict__ bucketCnt,
                                                          int* __restrict__ bucketBase) {
    __shared__ int sA[256];
    int t = threadIdx.x;
    int v = (t < NBUCK) ? bucketCnt[t] : 0;
    sA[t] = v;
    __syncthreads();
    for (int off = 1; off < 256; off <<= 1) {
        int x = (t >= off) ? sA[t - off] : 0;
        __syncthreads();
        sA[t] += x;
        __syncthreads();
    }
    if (t < NBUCK) bucketBase[t] = sA[t] - v;
    if (t == 0) bucketBase[NBUCK] = NEDGES;
}

__global__ __launch_bounds__(256) void bin_scatter_kernel(const int* __restrict__ edge,
                                                          const int* __restrict__ bucketBase,
                                                          int* __restrict__ bucketCursor,
                                                          unsigned int* __restrict__ binned) {
    __shared__ int sA[256];
    __shared__ int hcnt[NBUCK];
    __shared__ int hbase[NBUCK];
    __shared__ int gbase[NBUCK];
    __shared__ unsigned int sEnt[BCH];
    __shared__ unsigned char sBk[BCH];
    int t = threadIdx.x;
    int e0 = blockIdx.x * BCH;
    int nv = NEDGES - e0;
    if (nv > BCH) nv = BCH;

    if (t < NBUCK) hcnt[t] = 0;
    __syncthreads();

    int myB[8];
    int myR[8];
    unsigned int myP[8];
    #pragma unroll
    for (int j = 0; j < 8; ++j) {
        int idx = j * 256 + t;
        myB[j] = -1;
        if (idx < nv) {
            int s = edge[e0 + idx];
            int d = edge[NEDGES + e0 + idx];
            int bk = d >> 8;
            myB[j] = bk;
            myP[j] = (unsigned)s | ((unsigned)(d & 255) << 16);
            myR[j] = atomicAdd(&hcnt[bk], 1);    // LDS atomic, rank within (chunk,bucket)
        }
    }
    __syncthreads();
    int hc = (t < NBUCK) ? hcnt[t] : 0;
    sA[t] = hc;
    __syncthreads();
    for (int off = 1; off < 256; off <<= 1) {
        int x = (t >= off) ? sA[t - off] : 0;
        __syncthreads();
        sA[t] += x;
        __syncthreads();
    }
    if (t < NBUCK) {
        hbase[t] = sA[t] - hc;                               // chunk-local exclusive base
        gbase[t] = bucketBase[t] + atomicAdd(&bucketCursor[t], hc);  // one global atomic per (chunk,bucket)
    }
    __syncthreads();
    #pragma unroll
    for (int j = 0; j < 8; ++j) {
        if (myB[j] >= 0) {
            int p = hbase[myB[j]] + myR[j];
            sEnt[p] = myP[j];
            sBk[p] = (unsigned char)myB[j];
        }
    }
    __syncthreads();
    #pragma unroll
    for (int j = 0; j < 8; ++j) {
        int i = j * 256 + t;
        if (i < nv) {
            int bk = sBk[i];
            binned[gbase[bk] + (i - hbase[bk])] = sEnt[i];   // sorted order -> coalesced runs
        }
    }
}

__global__ __launch_bounds__(256) void fine_csr_kernel(const int* __restrict__ bucketCnt,
                                                       const int* __restrict__ bucketBase,
                                                       const unsigned int* __restrict__ binned,
                                                       int* __restrict__ offs,
                                                       int* __restrict__ csr) {
    __shared__ int sA[256];
    __shared__ int sB[256];
    int t = threadIdx.x;
    int b = blockIdx.x;
    int cntb = bucketCnt[b];
    int base = bucketBase[b];           // bucket's edge-region base
    sB[t] = 0;
    __syncthreads();
    for (int i = t; i < cntb; i += 256)
        atomicAdd(&sB[(binned[base + i] >> 16) & 255], 1);
    __syncthreads();
    int nc = sB[t];
    sA[t] = nc;
    __syncthreads();
    for (int off = 1; off < 256; off <<= 1) {
        int x = (t >= off) ? sA[t - off] : 0;
        __syncthreads();
        sA[t] += x;
        __syncthreads();
    }
    int nodeBase = base + sA[t] - nc;   // global csr start for this node
    int gid = b * 256 + t;
    if (gid < NNODES) offs[gid] = nodeBase;
    if (b == NBUCK - 1 && t == 0) offs[NNODES] = NEDGES;
    sB[t] = nodeBase;                   // becomes the LDS cursor (global positions)
    __syncthreads();
    for (int i = t; i < cntb; i += 256) {
        unsigned e = binned[base + i];
        int pos = atomicAdd(&sB[(e >> 16) & 255], 1);
        csr[pos] = (int)(e & 0xFFFFu);
    }
}

// ---------------------------------------------------------------- bn finalize: 64 slices -> scale/shift vector
__global__ __launch_bounds__(256) void bn_finalize_kernel(const float* __restrict__ statsPart,
                                                          const float* __restrict__ g,
                                                          const float* __restrict__ b,
                                                          float* __restrict__ ssv) {
    __shared__ float sm[256];
    int t = threadIdx.x;
    // t<128 sums s, t>=128 sums s2 (halves the serial chain)
    const float* base = statsPart + (t & 127) + ((t >> 7) << 7);
    float s = 0.f;
    #pragma unroll 8
    for (int k = 0; k < NSLICE; ++k) s += base[k * 512];
    sm[t] = s;
    __syncthreads();
    if (t < 128) {
        float mu = sm[t] / (float)NNODES;
        float var = sm[128 + t] / (float)NNODES - mu * mu;
        float rstd = rsqrtf(var + 1e-5f);
        float scale = g[t] * rstd;
        ssv[t] = scale;
        ssv[128 + t] = b[t] - mu * scale;
    }
}

// ---------------------------------------------------------------- MFMA GEMM [N,128]x[128,128]  (f16 pipeline)
//   mode 0: X = Xin
//   mode 1: X = elu(bn(Xin)); also write f16 X to Hw16 (=h1, skip source)
//   mode 2: X = skip16 + elu(bn(Xin))   (h3_in never materialized)
// R18 = R4's proven structure (best measured: total 360us, FETCH 13MB —
// L3 serves X across dispatches): B global->regs->LDS issued first, A loads
// in flight behind, fused bn+elu from precomputed ssv (1KB, L1-hot; replaces
// R4's inline 64-slice serial reduce), ONE barrier (Bs visibility), MFMA from
// LDS, wave-local transpose (in-order per-wave DS), fused epilogue.
// h1 is stored/read f16 (pk already computed for the A-panel) — halves skip
// traffic vs R4's f32 Hw. esrc/edst pre-scaled by log2(e).
#define GROWS 64
#define ASTRIDE 136
#define LOG2E 1.4426950408889634f
__global__ __launch_bounds__(256) void gemm_kernel(const float* __restrict__ Xin,
                                                   const unsigned short* __restrict__ skip16,
                                                   const float* __restrict__ ssv,
                                                   const unsigned short* __restrict__ Wt,
                                                   const float* __restrict__ a,
                                                   unsigned short* __restrict__ Hw16,
                                                   unsigned short* __restrict__ Hb,
                                                   float* __restrict__ esrc,
                                                   float* __restrict__ edst,
                                                   int mode) {
    __shared__ unsigned short As[GROWS * ASTRIDE];   // A: [m][k]  (f16)
    __shared__ unsigned short Bs[128 * ASTRIDE];     // B: [n][k]  (= W^T, f16)
    int tid = threadIdx.x;
    int rowBase = blockIdx.x * GROWS;

    // ---- issue all global loads up front (max memory-level parallelism)
    uint4 breg[8];
    #pragma unroll
    for (int q = 0; q < 8; ++q) {
        int i = q * 256 + tid;
        breg[q] = *(const uint4*)(Wt + (i >> 4) * 128 + (i & 15) * 8);
    }

    int r = tid >> 2;
    int cs = (tid & 3) * 32;
    int gr = rowBase + r;
    bool valid = gr < NNODES;
    float4 vv[8];
    if (valid) {
        #pragma unroll
        for (int j = 0; j < 8; ++j)
            vv[j] = *(const float4*)(Xin + (size_t)gr * HID + cs + j * 4);
    } else {
        #pragma unroll
        for (int j = 0; j < 8; ++j) vv[j] = make_float4(0.f, 0.f, 0.f, 0.f);
    }

    // ---- park B into LDS (waits only on breg; A loads still in flight)
    #pragma unroll
    for (int q = 0; q < 8; ++q) {
        int i = q * 256 + tid;
        *(uint4*)(&Bs[(i >> 4) * ASTRIDE + (i & 15) * 8]) = breg[q];
    }

    // ---- fused prev-layer bn+elu(+skip) on the A panel
    if (mode >= 1 && valid) {
        uint4 sk[4];
        if (mode == 2) {
            #pragma unroll
            for (int q = 0; q < 4; ++q)
                sk[q] = *(const uint4*)(skip16 + (size_t)gr * HID + cs + q * 8);
        }
        #pragma unroll
        for (int j = 0; j < 8; ++j) {
            int ch = cs + j * 4;
            float4 sc = *(const float4*)(ssv + ch);
            float4 sh = *(const float4*)(ssv + 128 + ch);
            float4 v = vv[j];
            v.x = sc.x * v.x + sh.x;
            v.y = sc.y * v.y + sh.y;
            v.z = sc.z * v.z + sh.z;
            v.w = sc.w * v.w + sh.w;
            v.x = (v.x > 0.f) ? v.x : expm1f(v.x);
            v.y = (v.y > 0.f) ? v.y : expm1f(v.y);
            v.z = (v.z > 0.f) ? v.z : expm1f(v.z);
            v.w = (v.w > 0.f) ? v.w : expm1f(v.w);
            if (mode == 2) {
                const unsigned int* pu = (const unsigned int*)&sk[j >> 1];
                half2v s0 = __builtin_bit_cast(half2v, pu[(j & 1) * 2]);
                half2v s1 = __builtin_bit_cast(half2v, pu[(j & 1) * 2 + 1]);
                v.x += (float)s0[0];
                v.y += (float)s0[1];
                v.z += (float)s1[0];
                v.w += (float)s1[1];
            }
            vv[j] = v;
        }
    }
    {
        unsigned int pk[16];
        #pragma unroll
        for (int j = 0; j < 8; ++j) {
            pk[2 * j]     = __builtin_bit_cast(unsigned int,
                                __builtin_amdgcn_cvt_pkrtz(vv[j].x, vv[j].y));
            pk[2 * j + 1] = __builtin_bit_cast(unsigned int,
                                __builtin_amdgcn_cvt_pkrtz(vv[j].z, vv[j].w));
        }
        if (mode == 1 && valid) {
            // h1 = pk (f16 post-activation X) — exactly what the A-panel uses
            #pragma unroll
            for (int q = 0; q < 4; ++q)
                *(uint4*)(Hw16 + (size_t)gr * HID + cs + q * 8) =
                    make_uint4(pk[4 * q], pk[4 * q + 1], pk[4 * q + 2], pk[4 * q + 3]);
        }
        #pragma unroll
        for (int q = 0; q < 4; ++q)
            *(uint4*)(&As[r * ASTRIDE + cs + q * 8]) =
                make_uint4(pk[4 * q], pk[4 * q + 1], pk[4 * q + 2], pk[4 * q + 3]);
    }

    __syncthreads();   // the ONLY barrier: Bs visibility across waves

    int wv = tid >> 6;
    int lane = tid & 63;
    int l15 = lane & 15;
    int quad = lane >> 4;
    const unsigned short* Arow = &As[(wv * 16 + l15) * ASTRIDE + quad * 8];
    half8 af[4];
    #pragma unroll
    for (int c = 0; c < 4; ++c) af[c] = *(const half8*)(Arow + c * 32);

    floatx4 acc[8];
    #pragma unroll
    for (int h = 0; h < 8; ++h) {
        acc[h] = (floatx4){0.f, 0.f, 0.f, 0.f};
        const unsigned short* Brow = &Bs[(h * 16 + l15) * ASTRIDE + quad * 8];
        #pragma unroll
        for (int c = 0; c < 4; ++c) {
            half8 bfr = *(const half8*)(Brow + c * 32);
            acc[h] = __builtin_amdgcn_mfma_f32_16x16x32_f16(af[c], bfr, acc[h], 0, 0, 0);
        }
    }

    // wave-local transpose through As (rows 16w..16w+15): no barrier needed,
    // per-wave DS ops execute in order.
    #pragma unroll
    for (int h = 0; h < 8; ++h) {
        #pragma unroll
        for (int reg = 0; reg < 4; ++reg)
            As[(wv * 16 + quad * 4 + reg) * ASTRIDE + h * 16 + l15] = f2h(acc[h][reg]);
    }

    {
        int rr = tid >> 2;
        int hp = tid & 3;                 // head pair
        int grr = rowBase + rr;
        const unsigned short* row = &As[rr * ASTRIDE + hp * 32];
        uint4 u[4];
        #pragma unroll
        for (int q = 0; q < 4; ++q) u[q] = *(const uint4*)(row + q * 8);
        if (grr < NNODES) {
            uint4* dst = (uint4*)(Hb + (size_t)grr * HID + hp * 32);
            #pragma unroll
            for (int q = 0; q < 4; ++q) dst[q] = u[q];
            float f[32];
            #pragma unroll
            for (int q = 0; q < 4; ++q) {
                unsigned int* pu = (unsigned int*)&u[q];
                #pragma unroll
                for (int j = 0; j < 4; ++j) {
                    half2v hv = __builtin_bit_cast(half2v, pu[j]);
                    f[q * 8 + 2 * j]     = (float)hv[0];
                    f[q * 8 + 2 * j + 1] = (float)hv[1];
                }
            }
            int h0 = hp * 2, h1 = hp * 2 + 1;
            float es0 = 0.f, ev0 = 0.f, es1 = 0.f, ev1 = 0.f;
            #pragma unroll
            for (int j = 0; j < 16; ++j) {
                es0 += f[j] * a[h0 * 32 + j];
                ev0 += f[j] * a[h0 * 32 + 16 + j];
                es1 += f[16 + j] * a[h1 * 32 + j];
                ev1 += f[16 + j] * a[h1 * 32 + 16 + j];
            }
            esrc[grr * NHEAD + h0] = es0 * LOG2E;
            esrc[grr * NHEAD + h1] = es1 * LOG2E;
            edst[grr * NHEAD + h0] = ev0 * LOG2E;
            edst[grr * NHEAD + h1] = ev1 * LOG2E;
        }
    }
}

// ---------------------------------------------------------------- softmax aggregation + sliced BN stats
// 4 nodes per wave (16 lanes/node, 8 channels/lane, uint4 Hb gathers).
// f16 h (v_fma_mix unpack), raw v_exp_f32 (log2e pre-folded), fmax LeakyReLU.
// Epilogue: 16-node LDS matrix -> 64-sliced global atomics.
__global__ __launch_bounds__(256) void aggregate_kernel(const int* __restrict__ offs,
                                                        const int* __restrict__ csr,
                                                        const float* __restrict__ esrc,
                                                        const float* __restrict__ edst,
                                                        const unsigned int* __restrict__ Hb,
                                                        float* __restrict__ out,
                                                        float* __restrict__ statsPart) {
    int tid = threadIdx.x;
    int wv = tid >> 6;
    int lane = tid & 63;
    int grp = lane >> 4;               // 4 node-groups per wave
    int sub = lane & 15;               // owns channels sub*8 .. sub*8+7
    int head = sub >> 1;
    int n = blockIdx.x * 16 + wv * 4 + grp;
    int beg = offs[n], end = offs[n + 1];
    float ed = edst[n * NHEAD + head];
    float acc[8];
    #pragma unroll
    for (int q = 0; q < 8; ++q) acc[q] = 0.f;
    float den = 0.f;
    for (int i = beg; i < end; i += 4) {
        int ss[4];
        #pragma unroll
        for (int j = 0; j < 4; ++j)
            ss[j] = csr[min(i + j, end - 1)];     // clamp: dup load, masked below
        float ee[4];
        uint4 hh[4];
        #pragma unroll
        for (int j = 0; j < 4; ++j)
            ee[j] = esrc[(unsigned)ss[j] * 8u + (unsigned)head];
        #pragma unroll
        for (int j = 0; j < 4; ++j)
            hh[j] = *(const uint4*)(Hb + (unsigned)ss[j] * 64u + (unsigned)sub * 4u);
        #pragma unroll
        for (int j = 0; j < 4; ++j) {
            float e = ee[j] + ed;
            e = fmaxf(e, 0.2f * e);               // LeakyReLU (pos-homog, log2e pre-folded)
            float w = fexp2(e);
            w = (i + j < end) ? w : 0.f;
            den += w;
            half2v h0 = __builtin_bit_cast(half2v, hh[j].x);
            half2v h1 = __builtin_bit_cast(half2v, hh[j].y);
            half2v h2 = __builtin_bit_cast(half2v, hh[j].z);
            half2v h3 = __builtin_bit_cast(half2v, hh[j].w);
            acc[0] += w * (float)h0[0];           // v_fma_mix_f32
            acc[1] += w * (float)h0[1];
            acc[2] += w * (float)h1[0];
            acc[3] += w * (float)h1[1];
            acc[4] += w * (float)h2[0];
            acc[5] += w * (float)h2[1];
            acc[6] += w * (float)h3[0];
            acc[7] += w * (float)h3[1];
        }
    }
    float inv = 1.f / (den + 1e-16f);
    float4 o0 = make_float4(acc[0] * inv, acc[1] * inv, acc[2] * inv, acc[3] * inv);
    float4 o1 = make_float4(acc[4] * inv, acc[5] * inv, acc[6] * inv, acc[7] * inv);
    float* orow = out + (size_t)n * HID + sub * 8;
    *(float4*)orow = o0;
    *(float4*)(orow + 4) = o1;

    // ---- BN partials: 16-node LDS matrix (pad stride 136), one barrier,
    // then 64-sliced global atomics.
    __shared__ float sm[16 * 136];
    float* srow = &sm[(wv * 4 + grp) * 136 + sub * 8];
    *(float4*)srow = o0;
    *(float4*)(srow + 4) = o1;
    __syncthreads();
    if (tid < 128) {
        float s = 0.f, s2 = 0.f;
        #pragma unroll
        for (int rr = 0; rr < 16; ++rr) {
            float v = sm[rr * 136 + tid];
            s += v;
            s2 += v * v;
        }
        float* slice = statsPart + (blockIdx.x & (NSLICE - 1)) * 512;
        atomicAdd(&slice[tid], s);
        atomicAdd(&slice[128 + tid], s2);
    }
}

// ---------------------------------------------------------------- final: apply BN from precomputed ssv
__global__ __launch_bounds__(256) void final_apply_kernel(const float* __restrict__ X,
                                                          const float* __restrict__ ssv,
                                                          float* __restrict__ out) {
    __shared__ float ssm[256];
    int tid = threadIdx.x;
    ssm[tid] = ssv[tid];
    __syncthreads();
    int total4 = NNODES * HID / 4;
    for (int i = blockIdx.x * 256 + tid; i < total4; i += gridDim.x * 256) {
        float4 v = ((const float4*)X)[i];
        int c4 = (i & 31) * 4;
        float4 sc = *(const float4*)(ssm + c4);
        float4 sh = *(const float4*)(ssm + 128 + c4);
        v.x = sc.x * v.x + sh.x;
        v.y = sc.y * v.y + sh.y;
        v.z = sc.z * v.z + sh.z;
        v.w = sc.w * v.w + sh.w;
        ((float4*)out)[i] = v;
    }
}

// ---------------------------------------------------------------- launch (15 dispatches)
extern "C" void kernel_launch(void* const* d_in, const int* in_sizes, int n_in,
                              void* d_out, int out_size, void* d_ws, size_t ws_size,
                              hipStream_t stream) {
    const float* x   = (const float*)d_in[0];
    const int* edge  = (const int*)d_in[1];
    const float* W1  = (const float*)d_in[2];
    const float* a1  = (const float*)d_in[3];
    const float* W2  = (const float*)d_in[4];
    const float* a2  = (const float*)d_in[5];
    const float* W3  = (const float*)d_in[6];
    const float* a3  = (const float*)d_in[7];
    const float* g1  = (const float*)d_in[8];
    const float* b1  = (const float*)d_in[9];
    const float* g2  = (const float*)d_in[10];
    const float* b2  = (const float*)d_in[11];
    const float* g3  = (const float*)d_in[12];
    const float* b3  = (const float*)d_in[13];
    float* outp      = (float*)d_out;

    char* p = (char*)d_ws;
    size_t cur = 0;
    auto carve = [&](size_t bytes) {
        void* r = p + cur;
        cur = align_up(cur + bytes, 256);
        return r;
    };
    int*   offs   = (int*)carve((NNODES + 1) * sizeof(int));
    int*   csr    = (int*)carve(NEDGES * sizeof(int));
    unsigned short* wt = (unsigned short*)carve(3 * 16384 * sizeof(unsigned short));
    unsigned short* hb = (unsigned short*)carve((size_t)NNODES * HID * sizeof(unsigned short));
    float* agg    = (float*)carve((size_t)NNODES * HID * sizeof(float));
    unsigned short* h1 = (unsigned short*)carve((size_t)NNODES * HID * sizeof(unsigned short));  // f16 now
    float* esrc   = (float*)carve((size_t)NNODES * NHEAD * sizeof(float));
    float* edst   = (float*)carve((size_t)NNODES * NHEAD * sizeof(float));
    float* stats  = (float*)carve(3 * SLAYER * sizeof(float));   // 64 slices x 512 floats x 3 layers
    int*   bcnt   = (int*)carve((3 * NBUCK + 1) * sizeof(int));  // bucketCnt + bucketCursor + bucketBase
    int*   bcur   = bcnt + NBUCK;
    int*   bbase  = bcnt + 2 * NBUCK;
    float* ssv    = (float*)carve(3 * 256 * sizeof(float));      // per-layer scale|shift
    float* stats1 = stats;
    float* stats2 = stats + SLAYER;
    float* stats3 = stats + 2 * SLAYER;
    float* ssv1 = ssv;
    float* ssv2 = ssv + 256;
    float* ssv3 = ssv + 512;
    // binned edge array (4B packed entries) aliases h1 (12.8MB >= 3.2MB):
    // h1 is first written by gemm layer-2 (mode 1), strictly after
    // fine_csr_kernel has consumed binned.
    unsigned int* binned = (unsigned int*)h1;

    const int GB = (NNODES + GROWS - 1) / GROWS;   // 782

    // ---- init (wconv + zero bucket counters/cursors + zero stats) + binned CSR build
    init_kernel<<<256, 256, 0, stream>>>(W1, W2, W3, wt,
                                         bcnt, 2 * NBUCK,
                                         stats, 3 * SLAYER);
    bin_count_kernel<<<256, 256, 0, stream>>>(edge, bcnt);
    bucket_scan_kernel<<<1, 256, 0, stream>>>(bcnt, bbase);
    bin_scatter_kernel<<<BIN_NB, 256, 0, stream>>>(edge, bbase, bcur, binned);
    fine_csr_kernel<<<NBUCK, 256, 0, stream>>>(bcnt, bbase, binned, offs, csr);

    // ---- layer 1
    gemm_kernel<<<GB, 256, 0, stream>>>(x, nullptr, nullptr,
                                        wt, a1, nullptr, hb, esrc, edst, 0);
    aggregate_kernel<<<AGG_NB, 256, 0, stream>>>(offs, csr, esrc, edst,
                                                 (const unsigned int*)hb, agg, stats1);
    bn_finalize_kernel<<<1, 256, 0, stream>>>(stats1, g1, b1, ssv1);

    // ---- layer 2 (gemm applies elu(bn1(agg)) inline, writes f16 h1)
    gemm_kernel<<<GB, 256, 0, stream>>>(agg, nullptr, ssv1,
                                        wt + 16384, a2, h1, hb, esrc, edst, 1);
    aggregate_kernel<<<AGG_NB, 256, 0, stream>>>(offs, csr, esrc, edst,
                                                 (const unsigned int*)hb, agg, stats2);
    bn_finalize_kernel<<<1, 256, 0, stream>>>(stats2, g2, b2, ssv2);

    // ---- layer 3 (gemm applies h1 + elu(bn2(agg)) inline, h1 read as f16)
    gemm_kernel<<<GB, 256, 0, stream>>>(agg, h1, ssv2,
                                        wt + 32768, a3, nullptr, hb, esrc, edst, 2);
    aggregate_kernel<<<AGG_NB, 256, 0, stream>>>(offs, csr, esrc, edst,
                                                 (const unsigned int*)hb, agg, stats3);
    bn_finalize_kernel<<<1, 256, 0, stream>>>(stats3, g3, b3, ssv3);

    // ---- final (applies bn3)
    final_apply_kernel<<<768, 256, 0, stream>>>(agg, ssv3, outp);
}

// Round 11
// 342.427 us; speedup vs baseline: 1.2604x; 1.0904x over previous
//
#include <hip/hip_runtime.h>
#include <hip/hip_bf16.h>
#include <hip/hip_fp16.h>
#include <cstddef>

#define NNODES 50000
#define NEDGES 800000
#define HID 128
#define NHEAD 8
#define AGG_NB (NNODES / 16)                           // 3125 (4 nodes per wave, 4 waves/block)
#define NSLICE 64                                      // stats slices
#define SLAYER (NSLICE * 512)                          // floats per layer of slice storage

// ---- binned CSR build
#define NBUCK 196                                      // ceil(50000/256) node-range buckets
#define BCH 2048                                       // edges per bin_scatter block
#define BIN_NB ((NEDGES + BCH - 1) / BCH)              // 391

#define GROWS 64
#define ASTRIDE 136
#define SMEM_BYTES 52224                               // As(17408B) + Bs(34816B)
#define LOG2E 1.4426950408889634f

typedef __attribute__((ext_vector_type(4))) float floatx4;
typedef _Float16 __attribute__((ext_vector_type(8))) half8;
typedef _Float16 __attribute__((ext_vector_type(2))) half2v;

static inline size_t align_up(size_t x, size_t a) { return (x + a - 1) & ~(a - 1); }

__device__ inline float fexp2(float x) {
#if __has_builtin(__builtin_amdgcn_exp2f)
    return __builtin_amdgcn_exp2f(x);          // raw v_exp_f32
#else
    return __expf(x * 0.69314718055994531f);   // e^(x ln2) = 2^x
#endif
}

__device__ inline unsigned short f2h(float f) {
    return __builtin_bit_cast(unsigned short, (_Float16)f);   // v_cvt_f16_f32 (RTE)
}

// ---------------------------------------------------------------- init: wconv (f32->f16) + all zero-fill (1 dispatch)
__global__ __launch_bounds__(256) void init_kernel(const float* __restrict__ W1,
                                                   const float* __restrict__ W2,
                                                   const float* __restrict__ W3,
                                                   unsigned short* __restrict__ Wt,
                                                   int* __restrict__ zeroA, int nA,
                                                   float* __restrict__ zeroB, int nB) {
    int b = blockIdx.x;
    int t = threadIdx.x;
    if (b < 192) {
        int layer = b >> 6;
        const float* W = (layer == 0) ? W1 : ((layer == 1) ? W2 : W3);
        int idx = (b & 63) * 256 + t;   // k*128+n
        int n = idx & 127;
        int k = idx >> 7;
        Wt[layer * 16384 + n * 128 + k] = f2h(W[idx]);
    } else {
        int nb = gridDim.x - 192;
        int bb = b - 192;
        for (int i = bb * 256 + t; i < nA; i += nb * 256) zeroA[i] = 0;
        for (int i = bb * 256 + t; i < nB; i += nb * 256) zeroB[i] = 0.f;
    }
}

// ---------------------------------------------------------------- binned CSR build (no per-edge global atomics)
__global__ __launch_bounds__(256) void bin_count_kernel(const int* __restrict__ edge,
                                                        int* __restrict__ bucketCnt) {
    __shared__ int h[NBUCK];
    int t = threadIdx.x;
    if (t < NBUCK) h[t] = 0;
    __syncthreads();
    for (int i = blockIdx.x * 256 + t; i < NEDGES; i += gridDim.x * 256)
        atomicAdd(&h[edge[NEDGES + i] >> 8], 1);
    __syncthreads();
    if (t < NBUCK && h[t]) atomicAdd(&bucketCnt[t], h[t]);
}

// one 2048-edge chunk per role-block: LDS rank -> LDS bucket-sorted reorder ->
// coalesced copy-out. Inline exclusive scan of the 196 bucket counts (R2/R3-proven).
__device__ __forceinline__ void scatter_block(char* smemraw, int bid, int t,
                                              const int* __restrict__ edge,
                                              const int* __restrict__ bucketCnt,
                                              int* __restrict__ bucketCursor,
                                              unsigned int* __restrict__ binned) {
    int* sA = (int*)smemraw;                    // 256
    int* hcnt = sA + 256;                       // 196
    int* hbase = hcnt + 196;                    // 196
    int* gbase = hbase + 196;                   // 196
    unsigned int* sEnt = (unsigned int*)(gbase + 196);   // 2048
    unsigned char* sBk = (unsigned char*)(sEnt + 2048);  // 2048
    int e0 = bid * BCH;
    int nv = NEDGES - e0;
    if (nv > BCH) nv = BCH;

    // inline exclusive scan of global bucket counts
    int gcnt = (t < NBUCK) ? bucketCnt[t] : 0;
    sA[t] = gcnt;
    __syncthreads();
    for (int off = 1; off < 256; off <<= 1) {
        int x = (t >= off) ? sA[t - off] : 0;
        __syncthreads();
        sA[t] += x;
        __syncthreads();
    }
    int gExBase = sA[t] - gcnt;
    if (t < NBUCK) hcnt[t] = 0;
    __syncthreads();

    int myB[8];
    int myR[8];
    unsigned int myP[8];
    #pragma unroll
    for (int j = 0; j < 8; ++j) {
        int idx = j * 256 + t;
        myB[j] = -1;
        if (idx < nv) {
            int s = edge[e0 + idx];
            int d = edge[NEDGES + e0 + idx];
            int bk = d >> 8;
            myB[j] = bk;
            myP[j] = (unsigned)s | ((unsigned)(d & 255) << 16);
            myR[j] = atomicAdd(&hcnt[bk], 1);    // LDS atomic, rank within (chunk,bucket)
        }
    }
    __syncthreads();
    int hc = (t < NBUCK) ? hcnt[t] : 0;
    sA[t] = hc;
    __syncthreads();
    for (int off = 1; off < 256; off <<= 1) {
        int x = (t >= off) ? sA[t - off] : 0;
        __syncthreads();
        sA[t] += x;
        __syncthreads();
    }
    if (t < NBUCK) {
        hbase[t] = sA[t] - hc;                               // chunk-local exclusive base
        gbase[t] = gExBase + atomicAdd(&bucketCursor[t], hc);  // one global atomic per (chunk,bucket)
    }
    __syncthreads();
    #pragma unroll
    for (int j = 0; j < 8; ++j) {
        if (myB[j] >= 0) {
            int p = hbase[myB[j]] + myR[j];
            sEnt[p] = myP[j];
            sBk[p] = (unsigned char)myB[j];
        }
    }
    __syncthreads();
    #pragma unroll
    for (int j = 0; j < 8; ++j) {
        int i = j * 256 + t;
        if (i < nv) {
            int bk = sBk[i];
            binned[gbase[bk] + (i - hbase[bk])] = sEnt[i];   // sorted order -> coalesced runs
        }
    }
}

// one block per bucket: per-node hist+cursor entirely in LDS; inline bucket scan.
__global__ __launch_bounds__(256) void fine_csr_kernel(const int* __restrict__ bucketCnt,
                                                       const unsigned int* __restrict__ binned,
                                                       int* __restrict__ offs,
                                                       int* __restrict__ csr) {
    __shared__ int sA[256];
    __shared__ int sB[256];
    int t = threadIdx.x;
    int b = blockIdx.x;
    int v = (t < NBUCK) ? bucketCnt[t] : 0;
    sA[t] = v;
    __syncthreads();
    for (int off = 1; off < 256; off <<= 1) {
        int x = (t >= off) ? sA[t - off] : 0;
        __syncthreads();
        sA[t] += x;
        __syncthreads();
    }
    int cntb = bucketCnt[b];
    int base = sA[b] - cntb;            // bucket's edge-region base
    sB[t] = 0;
    __syncthreads();
    for (int i = t; i < cntb; i += 256)
        atomicAdd(&sB[(binned[base + i] >> 16) & 255], 1);
    __syncthreads();
    int nc = sB[t];
    sA[t] = nc;
    __syncthreads();
    for (int off = 1; off < 256; off <<= 1) {
        int x = (t >= off) ? sA[t - off] : 0;
        __syncthreads();
        sA[t] += x;
        __syncthreads();
    }
    int nodeBase = base + sA[t] - nc;   // global csr start for this node
    int gid = b * 256 + t;
    if (gid < NNODES) offs[gid] = nodeBase;
    if (b == NBUCK - 1 && t == 0) offs[NNODES] = NEDGES;
    sB[t] = nodeBase;                   // becomes the LDS cursor (global positions)
    __syncthreads();
    for (int i = t; i < cntb; i += 256) {
        unsigned e = binned[base + i];
        int pos = atomicAdd(&sB[(e >> 16) & 255], 1);
        csr[pos] = (int)(e & 0xFFFFu);
    }
}

// ---------------------------------------------------------------- bn finalize: 64 slices -> scale/shift vector (layers 1,2)
__global__ __launch_bounds__(256) void bn_finalize_kernel(const float* __restrict__ statsPart,
                                                          const float* __restrict__ g,
                                                          const float* __restrict__ b,
                                                          float* __restrict__ ssv) {
    __shared__ float sm[256];
    int t = threadIdx.x;
    const float* base = statsPart + (t & 127) + ((t >> 7) << 7);
    float s = 0.f;
    #pragma unroll 8
    for (int k = 0; k < NSLICE; ++k) s += base[k * 512];
    sm[t] = s;
    __syncthreads();
    if (t < 128) {
        float mu = sm[t] / (float)NNODES;
        float var = sm[128 + t] / (float)NNODES - mu * mu;
        float rstd = rsqrtf(var + 1e-5f);
        float scale = g[t] * rstd;
        ssv[t] = scale;
        ssv[128 + t] = b[t] - mu * scale;
    }
}

// ---------------------------------------------------------------- MFMA GEMM body (R10-proven)
//   mode 0: X = Xin
//   mode 1: X = elu(bn(Xin)); also write f16 X to Hw16 (=h1, skip source)
//   mode 2: X = skip16 + elu(bn(Xin))
__device__ __forceinline__ void gemm_block(char* smemraw, int bid, int tid,
                                           const float* __restrict__ Xin,
                                           const unsigned short* __restrict__ skip16,
                                           const float* __restrict__ ssv,
                                           const unsigned short* __restrict__ Wt,
                                           const float* __restrict__ a,
                                           unsigned short* __restrict__ Hw16,
                                           unsigned short* __restrict__ Hb,
                                           float* __restrict__ esrc,
                                           float* __restrict__ edst,
                                           int mode) {
    unsigned short* As = (unsigned short*)smemraw;      // [64][136]
    unsigned short* Bs = As + GROWS * ASTRIDE;          // [128][136]
    int rowBase = bid * GROWS;

    // ---- issue all global loads up front (max memory-level parallelism)
    uint4 breg[8];
    #pragma unroll
    for (int q = 0; q < 8; ++q) {
        int i = q * 256 + tid;
        breg[q] = *(const uint4*)(Wt + (i >> 4) * 128 + (i & 15) * 8);
    }

    int r = tid >> 2;
    int cs = (tid & 3) * 32;
    int gr = rowBase + r;
    bool valid = gr < NNODES;
    float4 vv[8];
    if (valid) {
        #pragma unroll
        for (int j = 0; j < 8; ++j)
            vv[j] = *(const float4*)(Xin + (size_t)gr * HID + cs + j * 4);
    } else {
        #pragma unroll
        for (int j = 0; j < 8; ++j) vv[j] = make_float4(0.f, 0.f, 0.f, 0.f);
    }

    // ---- park B into LDS (waits only on breg; A loads still in flight)
    #pragma unroll
    for (int q = 0; q < 8; ++q) {
        int i = q * 256 + tid;
        *(uint4*)(&Bs[(i >> 4) * ASTRIDE + (i & 15) * 8]) = breg[q];
    }

    // ---- fused prev-layer bn+elu(+skip) on the A panel
    if (mode >= 1 && valid) {
        uint4 sk[4];
        if (mode == 2) {
            #pragma unroll
            for (int q = 0; q < 4; ++q)
                sk[q] = *(const uint4*)(skip16 + (size_t)gr * HID + cs + q * 8);
        }
        #pragma unroll
        for (int j = 0; j < 8; ++j) {
            int ch = cs + j * 4;
            float4 sc = *(const float4*)(ssv + ch);
            float4 sh = *(const float4*)(ssv + 128 + ch);
            float4 v = vv[j];
            v.x = sc.x * v.x + sh.x;
            v.y = sc.y * v.y + sh.y;
            v.z = sc.z * v.z + sh.z;
            v.w = sc.w * v.w + sh.w;
            v.x = (v.x > 0.f) ? v.x : expm1f(v.x);
            v.y = (v.y > 0.f) ? v.y : expm1f(v.y);
            v.z = (v.z > 0.f) ? v.z : expm1f(v.z);
            v.w = (v.w > 0.f) ? v.w : expm1f(v.w);
            if (mode == 2) {
                const unsigned int* pu = (const unsigned int*)&sk[j >> 1];
                half2v s0 = __builtin_bit_cast(half2v, pu[(j & 1) * 2]);
                half2v s1 = __builtin_bit_cast(half2v, pu[(j & 1) * 2 + 1]);
                v.x += (float)s0[0];
                v.y += (float)s0[1];
                v.z += (float)s1[0];
                v.w += (float)s1[1];
            }
            vv[j] = v;
        }
    }
    {
        unsigned int pk[16];
        #pragma unroll
        for (int j = 0; j < 8; ++j) {
            pk[2 * j]     = __builtin_bit_cast(unsigned int,
                                __builtin_amdgcn_cvt_pkrtz(vv[j].x, vv[j].y));
            pk[2 * j + 1] = __builtin_bit_cast(unsigned int,
                                __builtin_amdgcn_cvt_pkrtz(vv[j].z, vv[j].w));
        }
        if (mode == 1 && valid) {
            // h1 = pk (f16 post-activation X) — exactly what the A-panel uses
            #pragma unroll
            for (int q = 0; q < 4; ++q)
                *(uint4*)(Hw16 + (size_t)gr * HID + cs + q * 8) =
                    make_uint4(pk[4 * q], pk[4 * q + 1], pk[4 * q + 2], pk[4 * q + 3]);
        }
        #pragma unroll
        for (int q = 0; q < 4; ++q)
            *(uint4*)(&As[r * ASTRIDE + cs + q * 8]) =
                make_uint4(pk[4 * q], pk[4 * q + 1], pk[4 * q + 2], pk[4 * q + 3]);
    }

    __syncthreads();   // the ONLY barrier: Bs visibility across waves

    int wv = tid >> 6;
    int lane = tid & 63;
    int l15 = lane & 15;
    int quad = lane >> 4;
    const unsigned short* Arow = &As[(wv * 16 + l15) * ASTRIDE + quad * 8];
    half8 af[4];
    #pragma unroll
    for (int c = 0; c < 4; ++c) af[c] = *(const half8*)(Arow + c * 32);

    floatx4 acc[8];
    #pragma unroll
    for (int h = 0; h < 8; ++h) {
        acc[h] = (floatx4){0.f, 0.f, 0.f, 0.f};
        const unsigned short* Brow = &Bs[(h * 16 + l15) * ASTRIDE + quad * 8];
        #pragma unroll
        for (int c = 0; c < 4; ++c) {
            half8 bfr = *(const half8*)(Brow + c * 32);
            acc[h] = __builtin_amdgcn_mfma_f32_16x16x32_f16(af[c], bfr, acc[h], 0, 0, 0);
        }
    }

    // wave-local transpose through As (rows 16w..16w+15): no barrier needed,
    // per-wave DS ops execute in order.
    #pragma unroll
    for (int h = 0; h < 8; ++h) {
        #pragma unroll
        for (int reg = 0; reg < 4; ++reg)
            As[(wv * 16 + quad * 4 + reg) * ASTRIDE + h * 16 + l15] = f2h(acc[h][reg]);
    }

    {
        int rr = tid >> 2;
        int hp = tid & 3;                 // head pair
        int grr = rowBase + rr;
        const unsigned short* row = &As[rr * ASTRIDE + hp * 32];
        uint4 u[4];
        #pragma unroll
        for (int q = 0; q < 4; ++q) u[q] = *(const uint4*)(row + q * 8);
        if (grr < NNODES) {
            uint4* dst = (uint4*)(Hb + (size_t)grr * HID + hp * 32);
            #pragma unroll
            for (int q = 0; q < 4; ++q) dst[q] = u[q];
            float f[32];
            #pragma unroll
            for (int q = 0; q < 4; ++q) {
                unsigned int* pu = (unsigned int*)&u[q];
                #pragma unroll
                for (int j = 0; j < 4; ++j) {
                    half2v hv = __builtin_bit_cast(half2v, pu[j]);
                    f[q * 8 + 2 * j]     = (float)hv[0];
                    f[q * 8 + 2 * j + 1] = (float)hv[1];
                }
            }
            int h0 = hp * 2, h1 = hp * 2 + 1;
            float es0 = 0.f, ev0 = 0.f, es1 = 0.f, ev1 = 0.f;
            #pragma unroll
            for (int j = 0; j < 16; ++j) {
                es0 += f[j] * a[h0 * 32 + j];
                ev0 += f[j] * a[h0 * 32 + 16 + j];
                es1 += f[16 + j] * a[h1 * 32 + j];
                ev1 += f[16 + j] * a[h1 * 32 + 16 + j];
            }
            esrc[grr * NHEAD + h0] = es0 * LOG2E;
            esrc[grr * NHEAD + h1] = es1 * LOG2E;
            edst[grr * NHEAD + h0] = ev0 * LOG2E;
            edst[grr * NHEAD + h1] = ev1 * LOG2E;
        }
    }
}

// standalone gemm (layers 2,3)
__global__ __launch_bounds__(256) void gemm_kernel(const float* __restrict__ Xin,
                                                   const unsigned short* __restrict__ skip16,
                                                   const float* __restrict__ ssv,
                                                   const unsigned short* __restrict__ Wt,
                                                   const float* __restrict__ a,
                                                   unsigned short* __restrict__ Hw16,
                                                   unsigned short* __restrict__ Hb,
                                                   float* __restrict__ esrc,
                                                   float* __restrict__ edst,
                                                   int mode) {
    __shared__ char smem[SMEM_BYTES];
    gemm_block(smem, blockIdx.x, threadIdx.x, Xin, skip16, ssv, Wt, a,
               Hw16, Hb, esrc, edst, mode);
}

// fused: blocks [0, BIN_NB) run bin_scatter; blocks [BIN_NB, BIN_NB+GB) run
// layer-1 gemm (mode 0). The two roles share the 52KB LDS arena and have no
// data dependence (gemm1 needs only init's wconv; scatter needs bin_count).
__global__ __launch_bounds__(256) void gemm1_scatter_kernel(const float* __restrict__ Xin,
                                                            const unsigned short* __restrict__ Wt,
                                                            const float* __restrict__ a,
                                                            unsigned short* __restrict__ Hb,
                                                            float* __restrict__ esrc,
                                                            float* __restrict__ edst,
                                                            const int* __restrict__ edge,
                                                            const int* __restrict__ bucketCnt,
                                                            int* __restrict__ bucketCursor,
                                                            unsigned int* __restrict__ binned) {
    __shared__ char smem[SMEM_BYTES];
    int b = blockIdx.x;
    if (b < BIN_NB) {
        scatter_block(smem, b, threadIdx.x, edge, bucketCnt, bucketCursor, binned);
    } else {
        gemm_block(smem, b - BIN_NB, threadIdx.x, Xin, nullptr, nullptr, Wt, a,
                   nullptr, Hb, esrc, edst, 0);
    }
}

// ---------------------------------------------------------------- softmax aggregation + sliced BN stats
// 4 nodes per wave (16 lanes/node, 8 channels/lane, uint4 Hb gathers).
__global__ __launch_bounds__(256) void aggregate_kernel(const int* __restrict__ offs,
                                                        const int* __restrict__ csr,
                                                        const float* __restrict__ esrc,
                                                        const float* __restrict__ edst,
                                                        const unsigned int* __restrict__ Hb,
                                                        float* __restrict__ out,
                                                        float* __restrict__ statsPart) {
    int tid = threadIdx.x;
    int wv = tid >> 6;
    int lane = tid & 63;
    int grp = lane >> 4;               // 4 node-groups per wave
    int sub = lane & 15;               // owns channels sub*8 .. sub*8+7
    int head = sub >> 1;
    int n = blockIdx.x * 16 + wv * 4 + grp;
    int beg = offs[n], end = offs[n + 1];
    float ed = edst[n * NHEAD + head];
    float acc[8];
    #pragma unroll
    for (int q = 0; q < 8; ++q) acc[q] = 0.f;
    float den = 0.f;
    for (int i = beg; i < end; i += 4) {
        int ss[4];
        #pragma unroll
        for (int j = 0; j < 4; ++j)
            ss[j] = csr[min(i + j, end - 1)];     // clamp: dup load, masked below
        float ee[4];
        uint4 hh[4];
        #pragma unroll
        for (int j = 0; j < 4; ++j)
            ee[j] = esrc[(unsigned)ss[j] * 8u + (unsigned)head];
        #pragma unroll
        for (int j = 0; j < 4; ++j)
            hh[j] = *(const uint4*)(Hb + (unsigned)ss[j] * 64u + (unsigned)sub * 4u);
        #pragma unroll
        for (int j = 0; j < 4; ++j) {
            float e = ee[j] + ed;
            e = fmaxf(e, 0.2f * e);               // LeakyReLU (pos-homog, log2e pre-folded)
            float w = fexp2(e);
            w = (i + j < end) ? w : 0.f;
            den += w;
            half2v h0 = __builtin_bit_cast(half2v, hh[j].x);
            half2v h1 = __builtin_bit_cast(half2v, hh[j].y);
            half2v h2 = __builtin_bit_cast(half2v, hh[j].z);
            half2v h3 = __builtin_bit_cast(half2v, hh[j].w);
            acc[0] += w * (float)h0[0];           // v_fma_mix_f32
            acc[1] += w * (float)h0[1];
            acc[2] += w * (float)h1[0];
            acc[3] += w * (float)h1[1];
            acc[4] += w * (float)h2[0];
            acc[5] += w * (float)h2[1];
            acc[6] += w * (float)h3[0];
            acc[7] += w * (float)h3[1];
        }
    }
    float inv = 1.f / (den + 1e-16f);
    float4 o0 = make_float4(acc[0] * inv, acc[1] * inv, acc[2] * inv, acc[3] * inv);
    float4 o1 = make_float4(acc[4] * inv, acc[5] * inv, acc[6] * inv, acc[7] * inv);
    float* orow = out + (size_t)n * HID + sub * 8;
    *(float4*)orow = o0;
    *(float4*)(orow + 4) = o1;

    // ---- BN partials: 16-node LDS matrix (pad stride 136), one barrier,
    // then 64-sliced global atomics.
    __shared__ float sm[16 * 136];
    float* srow = &sm[(wv * 4 + grp) * 136 + sub * 8];
    *(float4*)srow = o0;
    *(float4*)(srow + 4) = o1;
    __syncthreads();
    if (tid < 128) {
        float s = 0.f, s2 = 0.f;
        #pragma unroll
        for (int rr = 0; rr < 16; ++rr) {
            float v = sm[rr * 136 + tid];
            s += v;
            s2 += v * v;
        }
        float* slice = statsPart + (blockIdx.x & (NSLICE - 1)) * 512;
        atomicAdd(&slice[tid], s);
        atomicAdd(&slice[128 + tid], s2);
    }
}

// ---------------------------------------------------------------- final: inline stats3 reduce + apply BN
__global__ __launch_bounds__(256) void final_apply_kernel(const float* __restrict__ X,
                                                          const float* __restrict__ statsPart,
                                                          const float* __restrict__ g,
                                                          const float* __restrict__ b,
                                                          float* __restrict__ out) {
    __shared__ float ssm[256];
    int tid = threadIdx.x;
    {
        const float* base = statsPart + (tid & 127) + ((tid >> 7) << 7);
        float s = 0.f;
        #pragma unroll 8
        for (int k = 0; k < NSLICE; ++k) s += base[k * 512];
        ssm[tid] = s;
    }
    __syncthreads();
    if (tid < 128) {
        float mu = ssm[tid] / (float)NNODES;
        float var = ssm[128 + tid] / (float)NNODES - mu * mu;
        float rstd = rsqrtf(var + 1e-5f);
        float scale = g[tid] * rstd;
        float shift = b[tid] - mu * scale;
        ssm[tid] = scale;
        ssm[128 + tid] = shift;
    }
    __syncthreads();
    int total4 = NNODES * HID / 4;
    for (int i = blockIdx.x * 256 + tid; i < total4; i += gridDim.x * 256) {
        float4 v = ((const float4*)X)[i];
        int c4 = (i & 31) * 4;
        float4 sc = *(const float4*)(ssm + c4);
        float4 sh = *(const float4*)(ssm + 128 + c4);
        v.x = sc.x * v.x + sh.x;
        v.y = sc.y * v.y + sh.y;
        v.z = sc.z * v.z + sh.z;
        v.w = sc.w * v.w + sh.w;
        ((float4*)out)[i] = v;
    }
}

// ---------------------------------------------------------------- launch (12 dispatches)
extern "C" void kernel_launch(void* const* d_in, const int* in_sizes, int n_in,
                              void* d_out, int out_size, void* d_ws, size_t ws_size,
                              hipStream_t stream) {
    const float* x   = (const float*)d_in[0];
    const int* edge  = (const int*)d_in[1];
    const float* W1  = (const float*)d_in[2];
    const float* a1  = (const float*)d_in[3];
    const float* W2  = (const float*)d_in[4];
    const float* a2  = (const float*)d_in[5];
    const float* W3  = (const float*)d_in[6];
    const float* a3  = (const float*)d_in[7];
    const float* g1  = (const float*)d_in[8];
    const float* b1  = (const float*)d_in[9];
    const float* g2  = (const float*)d_in[10];
    const float* b2  = (const float*)d_in[11];
    const float* g3  = (const float*)d_in[12];
    const float* b3  = (const float*)d_in[13];
    float* outp      = (float*)d_out;

    char* p = (char*)d_ws;
    size_t cur = 0;
    auto carve = [&](size_t bytes) {
        void* r = p + cur;
        cur = align_up(cur + bytes, 256);
        return r;
    };
    int*   offs   = (int*)carve((NNODES + 1) * sizeof(int));
    int*   csr    = (int*)carve(NEDGES * sizeof(int));
    unsigned short* wt = (unsigned short*)carve(3 * 16384 * sizeof(unsigned short));
    unsigned short* hb = (unsigned short*)carve((size_t)NNODES * HID * sizeof(unsigned short));
    float* agg    = (float*)carve((size_t)NNODES * HID * sizeof(float));
    unsigned short* h1 = (unsigned short*)carve((size_t)NNODES * HID * sizeof(unsigned short));  // f16
    float* esrc   = (float*)carve((size_t)NNODES * NHEAD * sizeof(float));
    float* edst   = (float*)carve((size_t)NNODES * NHEAD * sizeof(float));
    float* stats  = (float*)carve(3 * SLAYER * sizeof(float));   // 64 slices x 512 floats x 3 layers
    int*   bcnt   = (int*)carve(2 * NBUCK * sizeof(int));        // bucketCnt + bucketCursor
    int*   bcur   = bcnt + NBUCK;
    float* ssv    = (float*)carve(2 * 256 * sizeof(float));      // layer-1/2 scale|shift
    float* stats1 = stats;
    float* stats2 = stats + SLAYER;
    float* stats3 = stats + 2 * SLAYER;
    float* ssv1 = ssv;
    float* ssv2 = ssv + 256;
    // binned edge array (4B packed entries) aliases h1 (12.8MB >= 3.2MB):
    // h1 is first written by gemm layer-2 (mode 1), strictly after
    // fine_csr_kernel has consumed binned.
    unsigned int* binned = (unsigned int*)h1;

    const int GB = (NNODES + GROWS - 1) / GROWS;   // 782

    // ---- init (wconv + zero bucket counters/cursors + zero stats), hist
    init_kernel<<<256, 256, 0, stream>>>(W1, W2, W3, wt,
                                         bcnt, 2 * NBUCK,
                                         stats, 3 * SLAYER);
    bin_count_kernel<<<256, 256, 0, stream>>>(edge, bcnt);

    // ---- fused: bin_scatter (391 blocks) + layer-1 gemm (782 blocks)
    gemm1_scatter_kernel<<<BIN_NB + GB, 256, 0, stream>>>(x, wt, a1, hb, esrc, edst,
                                                          edge, bcnt, bcur, binned);
    fine_csr_kernel<<<NBUCK, 256, 0, stream>>>(bcnt, binned, offs, csr);

    // ---- layer 1 aggregate + bn1
    aggregate_kernel<<<AGG_NB, 256, 0, stream>>>(offs, csr, esrc, edst,
                                                 (const unsigned int*)hb, agg, stats1);
    bn_finalize_kernel<<<1, 256, 0, stream>>>(stats1, g1, b1, ssv1);

    // ---- layer 2 (gemm applies elu(bn1(agg)) inline, writes f16 h1)
    gemm_kernel<<<GB, 256, 0, stream>>>(agg, nullptr, ssv1,
                                        wt + 16384, a2, h1, hb, esrc, edst, 1);
    aggregate_kernel<<<AGG_NB, 256, 0, stream>>>(offs, csr, esrc, edst,
                                                 (const unsigned int*)hb, agg, stats2);
    bn_finalize_kernel<<<1, 256, 0, stream>>>(stats2, g2, b2, ssv2);

    // ---- layer 3 (gemm applies h1 + elu(bn2(agg)) inline, h1 read as f16)
    gemm_kernel<<<GB, 256, 0, stream>>>(agg, h1, ssv2,
                                        wt + 32768, a3, nullptr, hb, esrc, edst, 2);
    aggregate_kernel<<<AGG_NB, 256, 0, stream>>>(offs, csr, esrc, edst,
                                                 (const unsigned int*)hb, agg, stats3);

    // ---- final (inline stats3 reduce + bn3 apply)
    final_apply_kernel<<<768, 256, 0, stream>>>(agg, stats3, g3, b3, outp);
}

// Round 12
// 336.016 us; speedup vs baseline: 1.2844x; 1.0191x over previous
//
#include <hip/hip_runtime.h>
#include <hip/hip_bf16.h>
#include <hip/hip_fp16.h>
#include <cstddef>

#define NNODES 50000
#define NEDGES 800000
#define HID 128
#define NHEAD 8
#define AGG_NB (NNODES / 16)                           // 3125 (4 nodes per wave, 4 waves/block)
#define NSLICE 64                                      // stats slices
#define SLAYER (NSLICE * 512)                          // floats per layer of slice storage

// ---- binned CSR build
#define NBUCK 196                                      // ceil(50000/256) node-range buckets
#define BCH 2048                                       // edges per bin_scatter block
#define BIN_NB ((NEDGES + BCH - 1) / BCH)              // 391

#define GROWS 64
#define ASTRIDE 136
#define SMEM_BYTES 53248                               // As(17408) + Bs(34816) + ssm(1024)
#define LOG2E 1.4426950408889634f

typedef __attribute__((ext_vector_type(4))) float floatx4;
typedef _Float16 __attribute__((ext_vector_type(8))) half8;
typedef _Float16 __attribute__((ext_vector_type(2))) half2v;

static inline size_t align_up(size_t x, size_t a) { return (x + a - 1) & ~(a - 1); }

__device__ inline float fexp2(float x) {
#if __has_builtin(__builtin_amdgcn_exp2f)
    return __builtin_amdgcn_exp2f(x);          // raw v_exp_f32
#else
    return __expf(x * 0.69314718055994531f);   // e^(x ln2) = 2^x
#endif
}

__device__ inline unsigned short f2h(float f) {
    return __builtin_bit_cast(unsigned short, (_Float16)f);   // v_cvt_f16_f32 (RTE)
}

// ---------------------------------------------------------------- init: wconv (f32->f16) + all zero-fill (1 dispatch)
__global__ __launch_bounds__(256) void init_kernel(const float* __restrict__ W1,
                                                   const float* __restrict__ W2,
                                                   const float* __restrict__ W3,
                                                   unsigned short* __restrict__ Wt,
                                                   int* __restrict__ zeroA, int nA,
                                                   float* __restrict__ zeroB, int nB) {
    int b = blockIdx.x;
    int t = threadIdx.x;
    if (b < 192) {
        int layer = b >> 6;
        const float* W = (layer == 0) ? W1 : ((layer == 1) ? W2 : W3);
        int idx = (b & 63) * 256 + t;   // k*128+n
        int n = idx & 127;
        int k = idx >> 7;
        Wt[layer * 16384 + n * 128 + k] = f2h(W[idx]);
    } else {
        int nb = gridDim.x - 192;
        int bb = b - 192;
        for (int i = bb * 256 + t; i < nA; i += nb * 256) zeroA[i] = 0;
        for (int i = bb * 256 + t; i < nB; i += nb * 256) zeroB[i] = 0.f;
    }
}

// ---------------------------------------------------------------- binned CSR build (no per-edge global atomics)
__global__ __launch_bounds__(256) void bin_count_kernel(const int* __restrict__ edge,
                                                        int* __restrict__ bucketCnt) {
    __shared__ int h[NBUCK];
    int t = threadIdx.x;
    if (t < NBUCK) h[t] = 0;
    __syncthreads();
    for (int i = blockIdx.x * 256 + t; i < NEDGES; i += gridDim.x * 256)
        atomicAdd(&h[edge[NEDGES + i] >> 8], 1);
    __syncthreads();
    if (t < NBUCK && h[t]) atomicAdd(&bucketCnt[t], h[t]);
}

// one 2048-edge chunk per role-block: LDS rank -> LDS bucket-sorted reorder ->
// coalesced copy-out. Inline exclusive scan of the 196 bucket counts.
__device__ __forceinline__ void scatter_block(char* smemraw, int bid, int t,
                                              const int* __restrict__ edge,
                                              const int* __restrict__ bucketCnt,
                                              int* __restrict__ bucketCursor,
                                              unsigned int* __restrict__ binned) {
    int* sA = (int*)smemraw;                    // 256
    int* hcnt = sA + 256;                       // 196
    int* hbase = hcnt + 196;                    // 196
    int* gbase = hbase + 196;                   // 196
    unsigned int* sEnt = (unsigned int*)(gbase + 196);   // 2048
    unsigned char* sBk = (unsigned char*)(sEnt + 2048);  // 2048
    int e0 = bid * BCH;
    int nv = NEDGES - e0;
    if (nv > BCH) nv = BCH;

    // inline exclusive scan of global bucket counts
    int gcnt = (t < NBUCK) ? bucketCnt[t] : 0;
    sA[t] = gcnt;
    __syncthreads();
    for (int off = 1; off < 256; off <<= 1) {
        int x = (t >= off) ? sA[t - off] : 0;
        __syncthreads();
        sA[t] += x;
        __syncthreads();
    }
    int gExBase = sA[t] - gcnt;
    if (t < NBUCK) hcnt[t] = 0;
    __syncthreads();

    int myB[8];
    int myR[8];
    unsigned int myP[8];
    #pragma unroll
    for (int j = 0; j < 8; ++j) {
        int idx = j * 256 + t;
        myB[j] = -1;
        if (idx < nv) {
            int s = edge[e0 + idx];
            int d = edge[NEDGES + e0 + idx];
            int bk = d >> 8;
            myB[j] = bk;
            myP[j] = (unsigned)s | ((unsigned)(d & 255) << 16);
            myR[j] = atomicAdd(&hcnt[bk], 1);    // LDS atomic, rank within (chunk,bucket)
        }
    }
    __syncthreads();
    int hc = (t < NBUCK) ? hcnt[t] : 0;
    sA[t] = hc;
    __syncthreads();
    for (int off = 1; off < 256; off <<= 1) {
        int x = (t >= off) ? sA[t - off] : 0;
        __syncthreads();
        sA[t] += x;
        __syncthreads();
    }
    if (t < NBUCK) {
        hbase[t] = sA[t] - hc;                               // chunk-local exclusive base
        gbase[t] = gExBase + atomicAdd(&bucketCursor[t], hc);  // one global atomic per (chunk,bucket)
    }
    __syncthreads();
    #pragma unroll
    for (int j = 0; j < 8; ++j) {
        if (myB[j] >= 0) {
            int p = hbase[myB[j]] + myR[j];
            sEnt[p] = myP[j];
            sBk[p] = (unsigned char)myB[j];
        }
    }
    __syncthreads();
    #pragma unroll
    for (int j = 0; j < 8; ++j) {
        int i = j * 256 + t;
        if (i < nv) {
            int bk = sBk[i];
            binned[gbase[bk] + (i - hbase[bk])] = sEnt[i];   // sorted order -> coalesced runs
        }
    }
}

// one block per bucket: per-node hist+cursor entirely in LDS; inline bucket scan.
__global__ __launch_bounds__(256) void fine_csr_kernel(const int* __restrict__ bucketCnt,
                                                       const unsigned int* __restrict__ binned,
                                                       int* __restrict__ offs,
                                                       int* __restrict__ csr) {
    __shared__ int sA[256];
    __shared__ int sB[256];
    int t = threadIdx.x;
    int b = blockIdx.x;
    int v = (t < NBUCK) ? bucketCnt[t] : 0;
    sA[t] = v;
    __syncthreads();
    for (int off = 1; off < 256; off <<= 1) {
        int x = (t >= off) ? sA[t - off] : 0;
        __syncthreads();
        sA[t] += x;
        __syncthreads();
    }
    int cntb = bucketCnt[b];
    int base = sA[b] - cntb;            // bucket's edge-region base
    sB[t] = 0;
    __syncthreads();
    for (int i = t; i < cntb; i += 256)
        atomicAdd(&sB[(binned[base + i] >> 16) & 255], 1);
    __syncthreads();
    int nc = sB[t];
    sA[t] = nc;
    __syncthreads();
    for (int off = 1; off < 256; off <<= 1) {
        int x = (t >= off) ? sA[t - off] : 0;
        __syncthreads();
        sA[t] += x;
        __syncthreads();
    }
    int nodeBase = base + sA[t] - nc;   // global csr start for this node
    int gid = b * 256 + t;
    if (gid < NNODES) offs[gid] = nodeBase;
    if (b == NBUCK - 1 && t == 0) offs[NNODES] = NEDGES;
    sB[t] = nodeBase;                   // becomes the LDS cursor (global positions)
    __syncthreads();
    for (int i = t; i < cntb; i += 256) {
        unsigned e = binned[base + i];
        int pos = atomicAdd(&sB[(e >> 16) & 255], 1);
        csr[pos] = (int)(e & 0xFFFFu);
    }
}

// ---------------------------------------------------------------- MFMA GEMM body
//   mode 0: X = Xin
//   mode 1: X = elu(bn(Xin)); also write f16 X to Hw16 (=h1, skip source)
//   mode 2: X = skip16 + elu(bn(Xin))
// R12: bn_finalize inlined at gemm head with ZERO extra barriers — the one
// existing barrier (Bs visibility) also covers the ssm scale/shift table.
// Sequence: issue B/A/skip/stats loads -> park Bs -> tid<128 reduce 64 slices
// -> BARRIER -> bn apply from ssm -> pack -> wave-local As -> MFMA -> ...
__device__ __forceinline__ void gemm_block(char* smemraw, int bid, int tid,
                                           const float* __restrict__ Xin,
                                           const unsigned short* __restrict__ skip16,
                                           const float* __restrict__ statsPart,
                                           const float* __restrict__ gg,
                                           const float* __restrict__ bb,
                                           const unsigned short* __restrict__ Wt,
                                           const float* __restrict__ a,
                                           unsigned short* __restrict__ Hw16,
                                           unsigned short* __restrict__ Hb,
                                           float* __restrict__ esrc,
                                           float* __restrict__ edst,
                                           int mode) {
    unsigned short* As = (unsigned short*)smemraw;      // [64][136]
    unsigned short* Bs = As + GROWS * ASTRIDE;          // [128][136]
    float* ssm = (float*)(smemraw + 52224);             // scale[128] | shift[128]
    int rowBase = bid * GROWS;

    // ---- issue all global loads up front (max memory-level parallelism)
    uint4 breg[8];
    #pragma unroll
    for (int q = 0; q < 8; ++q) {
        int i = q * 256 + tid;
        breg[q] = *(const uint4*)(Wt + (i >> 4) * 128 + (i & 15) * 8);
    }

    int r = tid >> 2;
    int cs = (tid & 3) * 32;
    int gr = rowBase + r;
    bool valid = gr < NNODES;
    float4 vv[8];
    if (valid) {
        #pragma unroll
        for (int j = 0; j < 8; ++j)
            vv[j] = *(const float4*)(Xin + (size_t)gr * HID + cs + j * 4);
    } else {
        #pragma unroll
        for (int j = 0; j < 8; ++j) vv[j] = make_float4(0.f, 0.f, 0.f, 0.f);
    }
    uint4 sk[4];
    if (mode == 2 && valid) {
        #pragma unroll
        for (int q = 0; q < 4; ++q)
            sk[q] = *(const uint4*)(skip16 + (size_t)gr * HID + cs + q * 8);
    }

    // ---- park B into LDS (waits only on breg; A loads still in flight)
    #pragma unroll
    for (int q = 0; q < 8; ++q) {
        int i = q * 256 + tid;
        *(uint4*)(&Bs[(i >> 4) * ASTRIDE + (i & 15) * 8]) = breg[q];
    }

    // ---- inline bn finalize: 64 slices -> ssm (2 of 4 waves; pipelined L2 loads)
    if (mode >= 1 && tid < 128) {
        float s = 0.f, s2 = 0.f;
        #pragma unroll 8
        for (int k = 0; k < NSLICE; ++k) {
            s  += statsPart[k * 512 + tid];
            s2 += statsPart[k * 512 + 128 + tid];
        }
        float mu = s / (float)NNODES;
        float var = s2 / (float)NNODES - mu * mu;
        float rstd = rsqrtf(var + 1e-5f);
        float scale = gg[tid] * rstd;
        ssm[tid] = scale;
        ssm[128 + tid] = bb[tid] - mu * scale;
    }

    __syncthreads();   // the ONLY barrier: Bs + ssm visibility across waves

    // ---- fused prev-layer bn+elu(+skip) on the A panel
    if (mode >= 1 && valid) {
        #pragma unroll
        for (int j = 0; j < 8; ++j) {
            int ch = cs + j * 4;
            float4 sc = *(const float4*)(ssm + ch);
            float4 sh = *(const float4*)(ssm + 128 + ch);
            float4 v = vv[j];
            v.x = sc.x * v.x + sh.x;
            v.y = sc.y * v.y + sh.y;
            v.z = sc.z * v.z + sh.z;
            v.w = sc.w * v.w + sh.w;
            v.x = (v.x > 0.f) ? v.x : expm1f(v.x);
            v.y = (v.y > 0.f) ? v.y : expm1f(v.y);
            v.z = (v.z > 0.f) ? v.z : expm1f(v.z);
            v.w = (v.w > 0.f) ? v.w : expm1f(v.w);
            if (mode == 2) {
                const unsigned int* pu = (const unsigned int*)&sk[j >> 1];
                half2v s0 = __builtin_bit_cast(half2v, pu[(j & 1) * 2]);
                half2v s1 = __builtin_bit_cast(half2v, pu[(j & 1) * 2 + 1]);
                v.x += (float)s0[0];
                v.y += (float)s0[1];
                v.z += (float)s1[0];
                v.w += (float)s1[1];
            }
            vv[j] = v;
        }
    }
    {
        unsigned int pk[16];
        #pragma unroll
        for (int j = 0; j < 8; ++j) {
            pk[2 * j]     = __builtin_bit_cast(unsigned int,
                                __builtin_amdgcn_cvt_pkrtz(vv[j].x, vv[j].y));
            pk[2 * j + 1] = __builtin_bit_cast(unsigned int,
                                __builtin_amdgcn_cvt_pkrtz(vv[j].z, vv[j].w));
        }
        if (mode == 1 && valid) {
            // h1 = pk (f16 post-activation X) — exactly what the A-panel uses
            #pragma unroll
            for (int q = 0; q < 4; ++q)
                *(uint4*)(Hw16 + (size_t)gr * HID + cs + q * 8) =
                    make_uint4(pk[4 * q], pk[4 * q + 1], pk[4 * q + 2], pk[4 * q + 3]);
        }
        #pragma unroll
        for (int q = 0; q < 4; ++q)
            *(uint4*)(&As[r * ASTRIDE + cs + q * 8]) =
                make_uint4(pk[4 * q], pk[4 * q + 1], pk[4 * q + 2], pk[4 * q + 3]);
    }
    // NO second barrier: As rows are wave-local (written and read by the same
    // wave; per-wave DS ops execute in order).

    int wv = tid >> 6;
    int lane = tid & 63;
    int l15 = lane & 15;
    int quad = lane >> 4;
    const unsigned short* Arow = &As[(wv * 16 + l15) * ASTRIDE + quad * 8];
    half8 af[4];
    #pragma unroll
    for (int c = 0; c < 4; ++c) af[c] = *(const half8*)(Arow + c * 32);

    floatx4 acc[8];
    #pragma unroll
    for (int h = 0; h < 8; ++h) {
        acc[h] = (floatx4){0.f, 0.f, 0.f, 0.f};
        const unsigned short* Brow = &Bs[(h * 16 + l15) * ASTRIDE + quad * 8];
        #pragma unroll
        for (int c = 0; c < 4; ++c) {
            half8 bfr = *(const half8*)(Brow + c * 32);
            acc[h] = __builtin_amdgcn_mfma_f32_16x16x32_f16(af[c], bfr, acc[h], 0, 0, 0);
        }
    }

    // wave-local transpose through As (rows 16w..16w+15): no barrier needed.
    #pragma unroll
    for (int h = 0; h < 8; ++h) {
        #pragma unroll
        for (int reg = 0; reg < 4; ++reg)
            As[(wv * 16 + quad * 4 + reg) * ASTRIDE + h * 16 + l15] = f2h(acc[h][reg]);
    }

    {
        int rr = tid >> 2;
        int hp = tid & 3;                 // head pair
        int grr = rowBase + rr;
        const unsigned short* row = &As[rr * ASTRIDE + hp * 32];
        uint4 u[4];
        #pragma unroll
        for (int q = 0; q < 4; ++q) u[q] = *(const uint4*)(row + q * 8);
        if (grr < NNODES) {
            uint4* dst = (uint4*)(Hb + (size_t)grr * HID + hp * 32);
            #pragma unroll
            for (int q = 0; q < 4; ++q) dst[q] = u[q];
            float f[32];
            #pragma unroll
            for (int q = 0; q < 4; ++q) {
                unsigned int* pu = (unsigned int*)&u[q];
                #pragma unroll
                for (int j = 0; j < 4; ++j) {
                    half2v hv = __builtin_bit_cast(half2v, pu[j]);
                    f[q * 8 + 2 * j]     = (float)hv[0];
                    f[q * 8 + 2 * j + 1] = (float)hv[1];
                }
            }
            int h0 = hp * 2, h1 = hp * 2 + 1;
            float es0 = 0.f, ev0 = 0.f, es1 = 0.f, ev1 = 0.f;
            #pragma unroll
            for (int j = 0; j < 16; ++j) {
                es0 += f[j] * a[h0 * 32 + j];
                ev0 += f[j] * a[h0 * 32 + 16 + j];
                es1 += f[16 + j] * a[h1 * 32 + j];
                ev1 += f[16 + j] * a[h1 * 32 + 16 + j];
            }
            esrc[grr * NHEAD + h0] = es0 * LOG2E;
            esrc[grr * NHEAD + h1] = es1 * LOG2E;
            edst[grr * NHEAD + h0] = ev0 * LOG2E;
            edst[grr * NHEAD + h1] = ev1 * LOG2E;
        }
    }
}

// standalone gemm (layers 2,3)
__global__ __launch_bounds__(256) void gemm_kernel(const float* __restrict__ Xin,
                                                   const unsigned short* __restrict__ skip16,
                                                   const float* __restrict__ statsPart,
                                                   const float* __restrict__ gg,
                                                   const float* __restrict__ bb,
                                                   const unsigned short* __restrict__ Wt,
                                                   const float* __restrict__ a,
                                                   unsigned short* __restrict__ Hw16,
                                                   unsigned short* __restrict__ Hb,
                                                   float* __restrict__ esrc,
                                                   float* __restrict__ edst,
                                                   int mode) {
    __shared__ char smem[SMEM_BYTES];
    gemm_block(smem, blockIdx.x, threadIdx.x, Xin, skip16, statsPart, gg, bb,
               Wt, a, Hw16, Hb, esrc, edst, mode);
}

// fused: blocks [0, BIN_NB) run bin_scatter; blocks [BIN_NB, BIN_NB+GB) run
// layer-1 gemm (mode 0). The two roles share the LDS arena and have no
// data dependence (gemm1 needs only init's wconv; scatter needs bin_count).
__global__ __launch_bounds__(256) void gemm1_scatter_kernel(const float* __restrict__ Xin,
                                                            const unsigned short* __restrict__ Wt,
                                                            const float* __restrict__ a,
                                                            unsigned short* __restrict__ Hb,
                                                            float* __restrict__ esrc,
                                                            float* __restrict__ edst,
                                                            const int* __restrict__ edge,
                                                            const int* __restrict__ bucketCnt,
                                                            int* __restrict__ bucketCursor,
                                                            unsigned int* __restrict__ binned) {
    __shared__ char smem[SMEM_BYTES];
    int b = blockIdx.x;
    if (b < BIN_NB) {
        scatter_block(smem, b, threadIdx.x, edge, bucketCnt, bucketCursor, binned);
    } else {
        gemm_block(smem, b - BIN_NB, threadIdx.x, Xin, nullptr, nullptr, nullptr, nullptr,
                   Wt, a, nullptr, Hb, esrc, edst, 0);
    }
}

// ---------------------------------------------------------------- softmax aggregation + sliced BN stats
// 4 nodes per wave (16 lanes/node, 8 channels/lane, uint4 Hb gathers).
__global__ __launch_bounds__(256) void aggregate_kernel(const int* __restrict__ offs,
                                                        const int* __restrict__ csr,
                                                        const float* __restrict__ esrc,
                                                        const float* __restrict__ edst,
                                                        const unsigned int* __restrict__ Hb,
                                                        float* __restrict__ out,
                                                        float* __restrict__ statsPart) {
    int tid = threadIdx.x;
    int wv = tid >> 6;
    int lane = tid & 63;
    int grp = lane >> 4;               // 4 node-groups per wave
    int sub = lane & 15;               // owns channels sub*8 .. sub*8+7
    int head = sub >> 1;
    int n = blockIdx.x * 16 + wv * 4 + grp;
    int beg = offs[n], end = offs[n + 1];
    float ed = edst[n * NHEAD + head];
    float acc[8];
    #pragma unroll
    for (int q = 0; q < 8; ++q) acc[q] = 0.f;
    float den = 0.f;
    for (int i = beg; i < end; i += 4) {
        int ss[4];
        #pragma unroll
        for (int j = 0; j < 4; ++j)
            ss[j] = csr[min(i + j, end - 1)];     // clamp: dup load, masked below
        float ee[4];
        uint4 hh[4];
        #pragma unroll
        for (int j = 0; j < 4; ++j)
            ee[j] = esrc[(unsigned)ss[j] * 8u + (unsigned)head];
        #pragma unroll
        for (int j = 0; j < 4; ++j)
            hh[j] = *(const uint4*)(Hb + (unsigned)ss[j] * 64u + (unsigned)sub * 4u);
        #pragma unroll
        for (int j = 0; j < 4; ++j) {
            float e = ee[j] + ed;
            e = fmaxf(e, 0.2f * e);               // LeakyReLU (pos-homog, log2e pre-folded)
            float w = fexp2(e);
            w = (i + j < end) ? w : 0.f;
            den += w;
            half2v h0 = __builtin_bit_cast(half2v, hh[j].x);
            half2v h1 = __builtin_bit_cast(half2v, hh[j].y);
            half2v h2 = __builtin_bit_cast(half2v, hh[j].z);
            half2v h3 = __builtin_bit_cast(half2v, hh[j].w);
            acc[0] += w * (float)h0[0];           // v_fma_mix_f32
            acc[1] += w * (float)h0[1];
            acc[2] += w * (float)h1[0];
            acc[3] += w * (float)h1[1];
            acc[4] += w * (float)h2[0];
            acc[5] += w * (float)h2[1];
            acc[6] += w * (float)h3[0];
            acc[7] += w * (float)h3[1];
        }
    }
    float inv = 1.f / (den + 1e-16f);
    float4 o0 = make_float4(acc[0] * inv, acc[1] * inv, acc[2] * inv, acc[3] * inv);
    float4 o1 = make_float4(acc[4] * inv, acc[5] * inv, acc[6] * inv, acc[7] * inv);
    float* orow = out + (size_t)n * HID + sub * 8;
    *(float4*)orow = o0;
    *(float4*)(orow + 4) = o1;

    // ---- BN partials: 16-node LDS matrix (pad stride 136), one barrier,
    // then 64-sliced global atomics.
    __shared__ float sm[16 * 136];
    float* srow = &sm[(wv * 4 + grp) * 136 + sub * 8];
    *(float4*)srow = o0;
    *(float4*)(srow + 4) = o1;
    __syncthreads();
    if (tid < 128) {
        float s = 0.f, s2 = 0.f;
        #pragma unroll
        for (int rr = 0; rr < 16; ++rr) {
            float v = sm[rr * 136 + tid];
            s += v;
            s2 += v * v;
        }
        float* slice = statsPart + (blockIdx.x & (NSLICE - 1)) * 512;
        atomicAdd(&slice[tid], s);
        atomicAdd(&slice[128 + tid], s2);
    }
}

// ---------------------------------------------------------------- final: inline stats3 reduce + apply BN
__global__ __launch_bounds__(256) void final_apply_kernel(const float* __restrict__ X,
                                                          const float* __restrict__ statsPart,
                                                          const float* __restrict__ g,
                                                          const float* __restrict__ b,
                                                          float* __restrict__ out) {
    __shared__ float ssm[256];
    int tid = threadIdx.x;
    {
        const float* base = statsPart + (tid & 127) + ((tid >> 7) << 7);
        float s = 0.f;
        #pragma unroll 8
        for (int k = 0; k < NSLICE; ++k) s += base[k * 512];
        ssm[tid] = s;
    }
    __syncthreads();
    if (tid < 128) {
        float mu = ssm[tid] / (float)NNODES;
        float var = ssm[128 + tid] / (float)NNODES - mu * mu;
        float rstd = rsqrtf(var + 1e-5f);
        float scale = g[tid] * rstd;
        float shift = b[tid] - mu * scale;
        ssm[tid] = scale;
        ssm[128 + tid] = shift;
    }
    __syncthreads();
    int total4 = NNODES * HID / 4;
    for (int i = blockIdx.x * 256 + tid; i < total4; i += gridDim.x * 256) {
        float4 v = ((const float4*)X)[i];
        int c4 = (i & 31) * 4;
        float4 sc = *(const float4*)(ssm + c4);
        float4 sh = *(const float4*)(ssm + 128 + c4);
        v.x = sc.x * v.x + sh.x;
        v.y = sc.y * v.y + sh.y;
        v.z = sc.z * v.z + sh.z;
        v.w = sc.w * v.w + sh.w;
        ((float4*)out)[i] = v;
    }
}

// ---------------------------------------------------------------- launch (10 dispatches)
extern "C" void kernel_launch(void* const* d_in, const int* in_sizes, int n_in,
                              void* d_out, int out_size, void* d_ws, size_t ws_size,
                              hipStream_t stream) {
    const float* x   = (const float*)d_in[0];
    const int* edge  = (const int*)d_in[1];
    const float* W1  = (const float*)d_in[2];
    const float* a1  = (const float*)d_in[3];
    const float* W2  = (const float*)d_in[4];
    const float* a2  = (const float*)d_in[5];
    const float* W3  = (const float*)d_in[6];
    const float* a3  = (const float*)d_in[7];
    const float* g1  = (const float*)d_in[8];
    const float* b1  = (const float*)d_in[9];
    const float* g2  = (const float*)d_in[10];
    const float* b2  = (const float*)d_in[11];
    const float* g3  = (const float*)d_in[12];
    const float* b3  = (const float*)d_in[13];
    float* outp      = (float*)d_out;

    char* p = (char*)d_ws;
    size_t cur = 0;
    auto carve = [&](size_t bytes) {
        void* r = p + cur;
        cur = align_up(cur + bytes, 256);
        return r;
    };
    int*   offs   = (int*)carve((NNODES + 1) * sizeof(int));
    int*   csr    = (int*)carve(NEDGES * sizeof(int));
    unsigned short* wt = (unsigned short*)carve(3 * 16384 * sizeof(unsigned short));
    unsigned short* hb = (unsigned short*)carve((size_t)NNODES * HID * sizeof(unsigned short));
    float* agg    = (float*)carve((size_t)NNODES * HID * sizeof(float));
    unsigned short* h1 = (unsigned short*)carve((size_t)NNODES * HID * sizeof(unsigned short));  // f16
    float* esrc   = (float*)carve((size_t)NNODES * NHEAD * sizeof(float));
    float* edst   = (float*)carve((size_t)NNODES * NHEAD * sizeof(float));
    float* stats  = (float*)carve(3 * SLAYER * sizeof(float));   // 64 slices x 512 floats x 3 layers
    int*   bcnt   = (int*)carve(2 * NBUCK * sizeof(int));        // bucketCnt + bucketCursor
    int*   bcur   = bcnt + NBUCK;
    float* stats1 = stats;
    float* stats2 = stats + SLAYER;
    float* stats3 = stats + 2 * SLAYER;
    // binned edge array (4B packed entries) aliases h1 (12.8MB >= 3.2MB):
    // h1 is first written by gemm layer-2 (mode 1), strictly after
    // fine_csr_kernel has consumed binned.
    unsigned int* binned = (unsigned int*)h1;

    const int GB = (NNODES + GROWS - 1) / GROWS;   // 782

    // ---- init (wconv + zero bucket counters/cursors + zero stats), hist
    init_kernel<<<256, 256, 0, stream>>>(W1, W2, W3, wt,
                                         bcnt, 2 * NBUCK,
                                         stats, 3 * SLAYER);
    bin_count_kernel<<<256, 256, 0, stream>>>(edge, bcnt);

    // ---- fused: bin_scatter (391 blocks) + layer-1 gemm (782 blocks)
    gemm1_scatter_kernel<<<BIN_NB + GB, 256, 0, stream>>>(x, wt, a1, hb, esrc, edst,
                                                          edge, bcnt, bcur, binned);
    fine_csr_kernel<<<NBUCK, 256, 0, stream>>>(bcnt, binned, offs, csr);

    // ---- layer 1 aggregate
    aggregate_kernel<<<AGG_NB, 256, 0, stream>>>(offs, csr, esrc, edst,
                                                 (const unsigned int*)hb, agg, stats1);

    // ---- layer 2 (gemm inlines bn1 finalize + elu, writes f16 h1)
    gemm_kernel<<<GB, 256, 0, stream>>>(agg, nullptr, stats1, g1, b1,
                                        wt + 16384, a2, h1, hb, esrc, edst, 1);
    aggregate_kernel<<<AGG_NB, 256, 0, stream>>>(offs, csr, esrc, edst,
                                                 (const unsigned int*)hb, agg, stats2);

    // ---- layer 3 (gemm inlines bn2 finalize + elu + skip, h1 read as f16)
    gemm_kernel<<<GB, 256, 0, stream>>>(agg, h1, stats2, g2, b2,
                                        wt + 32768, a3, nullptr, hb, esrc, edst, 2);
    aggregate_kernel<<<AGG_NB, 256, 0, stream>>>(offs, csr, esrc, edst,
                                                 (const unsigned int*)hb, agg, stats3);

    // ---- final (inline stats3 reduce + bn3 apply)
    final_apply_kernel<<<768, 256, 0, stream>>>(agg, stats3, g3, b3, outp);
}